// Round 1
// baseline (288.477 us; speedup 1.0000x reference)
//
#include <hip/hip_runtime.h>

#define Bn 4
#define Tn 2048
#define Dn 1024
#define HSn 64
#define ROWS 8      // rows per projection block
#define TILE 64     // K/V tile (s dimension)

// ---------------- Projection: q/k/v = x @ {Wq,Wk,Wv} ----------------
__global__ __launch_bounds__(256) void proj_kernel(
    const float* __restrict__ x,
    const float* __restrict__ Wk,
    const float* __restrict__ Wq,
    const float* __restrict__ Wv,
    float* __restrict__ qo, float* __restrict__ ko, float* __restrict__ vo)
{
    __shared__ float xs[ROWS * Dn];  // 32 KB
    const int tid = threadIdx.x;
    const long row0 = (long)blockIdx.x * ROWS;

    {
        const float4* src = (const float4*)(x + row0 * Dn);
        float4* dst = (float4*)xs;
        #pragma unroll
        for (int i = 0; i < (ROWS * Dn / 4) / 256; ++i)
            dst[tid + 256 * i] = src[tid + 256 * i];
    }
    __syncthreads();

    const int proj = tid >> 6;
    const int h = tid & 63;
    if (proj < 3) {
        const float* __restrict__ W = (proj == 0) ? Wq : (proj == 1) ? Wk : Wv;
        float*       __restrict__ o = (proj == 0) ? qo : (proj == 1) ? ko : vo;
        float acc[ROWS];
        #pragma unroll
        for (int r = 0; r < ROWS; ++r) acc[r] = 0.f;
        for (int d = 0; d < Dn; d += 4) {
            const float w0 = W[(d + 0) * HSn + h];
            const float w1 = W[(d + 1) * HSn + h];
            const float w2 = W[(d + 2) * HSn + h];
            const float w3 = W[(d + 3) * HSn + h];
            #pragma unroll
            for (int r = 0; r < ROWS; ++r) {
                const float4 xv = *(const float4*)&xs[r * Dn + d];
                acc[r] = fmaf(xv.w, w3, fmaf(xv.z, w2, fmaf(xv.y, w1, fmaf(xv.x, w0, acc[r]))));
            }
        }
        #pragma unroll
        for (int r = 0; r < ROWS; ++r)
            o[(row0 + r) * HSn + h] = acc[r];
    }
}

// ---------------- Flash attention, causal, scale = *sqrt(HS) = *8 ----------------
__global__ __launch_bounds__(256) void attn_kernel(
    const float* __restrict__ q,
    const float* __restrict__ k,
    const float* __restrict__ v,
    float* __restrict__ out)
{
    __shared__ float Ks[TILE][HSn + 1];
    __shared__ float Vs[TILE][HSn + 1];
    __shared__ float qs[4][HSn];
    __shared__ float ps[4][TILE];

    const int blk  = blockIdx.x;
    const int b    = blk >> 9;
    const int rb   = blk & 511;
    const int t0   = rb * 4;
    const int wave = threadIdx.x >> 6;
    const int lane = threadIdx.x & 63;
    const int t    = t0 + wave;

    const float* __restrict__ qb = q + (size_t)b * Tn * HSn;
    const float* __restrict__ kb = k + (size_t)b * Tn * HSn;
    const float* __restrict__ vb = v + (size_t)b * Tn * HSn;

    qs[wave][lane] = qb[(size_t)t * HSn + lane];

    float m = -1e30f, l = 0.f, acc = 0.f;
    const int ntiles = (t0 + 3) / TILE + 1;

    for (int j = 0; j < ntiles; ++j) {
        const int s0 = j * TILE;
        __syncthreads();
        {
            const float4* ksrc = (const float4*)(kb + (size_t)s0 * HSn);
            const float4* vsrc = (const float4*)(vb + (size_t)s0 * HSn);
            #pragma unroll
            for (int i = 0; i < 4; ++i) {
                const int f4 = threadIdx.x * 4 + i;   // 0..1023
                const int sl = f4 >> 4;
                const int hh = (f4 << 2) & 63;
                const float4 kv = ksrc[f4];
                Ks[sl][hh + 0] = kv.x; Ks[sl][hh + 1] = kv.y;
                Ks[sl][hh + 2] = kv.z; Ks[sl][hh + 3] = kv.w;
                const float4 vv = vsrc[f4];
                Vs[sl][hh + 0] = vv.x; Vs[sl][hh + 1] = vv.y;
                Vs[sl][hh + 2] = vv.z; Vs[sl][hh + 3] = vv.w;
            }
        }
        __syncthreads();

        if (s0 <= t) {
            const int s = s0 + lane;
            float dot = 0.f;
            #pragma unroll 16
            for (int h = 0; h < HSn; ++h)
                dot = fmaf(qs[wave][h], Ks[lane][h], dot);
            float sc = dot * 8.0f;
            if (s > t) sc = -1e30f;

            float mx = sc;
            #pragma unroll
            for (int off = 32; off > 0; off >>= 1)
                mx = fmaxf(mx, __shfl_xor(mx, off));
            const float mnew = fmaxf(m, mx);

            const float p = __expf(sc - mnew);
            float psum = p;
            #pragma unroll
            for (int off = 32; off > 0; off >>= 1)
                psum += __shfl_xor(psum, off);

            const float alpha = __expf(m - mnew);
            l = l * alpha + psum;

            ps[wave][lane] = p;
            float a2 = acc * alpha;
            #pragma unroll 16
            for (int s2 = 0; s2 < TILE; ++s2)
                a2 = fmaf(ps[wave][s2], Vs[s2][lane], a2);
            acc = a2;
            m = mnew;
        }
    }
    out[((size_t)b * Tn + t) * HSn + lane] = acc / l;
}

extern "C" void kernel_launch(void* const* d_in, const int* in_sizes, int n_in,
                              void* d_out, int out_size, void* d_ws, size_t ws_size,
                              hipStream_t stream) {
    const float* x  = (const float*)d_in[0];
    const float* Wk = (const float*)d_in[1];
    const float* Wq = (const float*)d_in[2];
    const float* Wv = (const float*)d_in[3];
    float* out = (float*)d_out;

    const size_t per = (size_t)Bn * Tn * HSn;   // 524288 floats
    float* qw = (float*)d_ws;
    float* kw = qw + per;
    float* vw = kw + per;

    hipLaunchKernelGGL(proj_kernel, dim3(Bn * Tn / ROWS), dim3(256), 0, stream,
                       x, Wk, Wq, Wv, qw, kw, vw);
    hipLaunchKernelGGL(attn_kernel, dim3(Bn * Tn / 4), dim3(256), 0, stream,
                       qw, kw, vw, out);
}

// Round 2
// 137.230 us; speedup vs baseline: 2.1021x; 2.1021x over previous
//
#include <hip/hip_runtime.h>

#define Bn 4
#define Tn 2048
#define Dn 1024
#define HSn 64
#define ROWS 8

typedef __attribute__((ext_vector_type(8))) short bf16x8;
typedef __attribute__((ext_vector_type(4))) float f32x4;
typedef unsigned short u16;
typedef unsigned int u32;

__device__ __forceinline__ u16 f2bf_rne(float x) {
    u32 u = __float_as_uint(x);
    return (u16)((u + 0x7FFFu + ((u >> 16) & 1u)) >> 16);
}
__device__ __forceinline__ u16 f2bf_trunc(float x) {
    return (u16)(__float_as_uint(x) >> 16);
}
__device__ __forceinline__ float bf2f(u16 h) {
    return __uint_as_float(((u32)h) << 16);
}

// ---------------- Projection: q/k/v = x @ {Wq,Wk,Wv} ----------------
// Emits: qh8/ql8 = hi/lo bf16 split of 8*q (scale folded), kh/kl = split of k,
//        vt = bf16 V transposed to [B][HS][T] for direct B-fragment staging.
__global__ __launch_bounds__(256) void proj_kernel(
    const float* __restrict__ x,
    const float* __restrict__ Wk,
    const float* __restrict__ Wq,
    const float* __restrict__ Wv,
    u16* __restrict__ qh8, u16* __restrict__ ql8,
    u16* __restrict__ kh,  u16* __restrict__ kl,
    u16* __restrict__ vt)
{
    __shared__ float xs[ROWS * Dn];  // 32 KB
    const int tid = threadIdx.x;
    const long row0 = (long)blockIdx.x * ROWS;

    {
        const float4* src = (const float4*)(x + row0 * Dn);
        float4* dst = (float4*)xs;
        #pragma unroll
        for (int i = 0; i < (ROWS * Dn / 4) / 256; ++i)
            dst[tid + 256 * i] = src[tid + 256 * i];
    }
    __syncthreads();

    const int proj = tid >> 6;
    const int h = tid & 63;
    if (proj < 3) {
        const float* __restrict__ W = (proj == 0) ? Wq : (proj == 1) ? Wk : Wv;
        float acc[ROWS];
        #pragma unroll
        for (int r = 0; r < ROWS; ++r) acc[r] = 0.f;
        for (int d = 0; d < Dn; d += 4) {
            const float w0 = W[(d + 0) * HSn + h];
            const float w1 = W[(d + 1) * HSn + h];
            const float w2 = W[(d + 2) * HSn + h];
            const float w3 = W[(d + 3) * HSn + h];
            #pragma unroll
            for (int r = 0; r < ROWS; ++r) {
                const float4 xv = *(const float4*)&xs[r * Dn + d];
                acc[r] = fmaf(xv.w, w3, fmaf(xv.z, w2, fmaf(xv.y, w1, fmaf(xv.x, w0, acc[r]))));
            }
        }
        if (proj == 0) {
            #pragma unroll
            for (int r = 0; r < ROWS; ++r) {
                float s8 = acc[r] * 8.0f;       // fold the *sqrt(HS) score scale
                u16 hi = f2bf_trunc(s8);
                float rem = s8 - bf2f(hi);
                qh8[(row0 + r) * HSn + h] = hi;
                ql8[(row0 + r) * HSn + h] = f2bf_trunc(rem);
            }
        } else if (proj == 1) {
            #pragma unroll
            for (int r = 0; r < ROWS; ++r) {
                u16 hi = f2bf_trunc(acc[r]);
                float rem = acc[r] - bf2f(hi);
                kh[(row0 + r) * HSn + h] = hi;
                kl[(row0 + r) * HSn + h] = f2bf_trunc(rem);
            }
        } else {
            const int b  = (int)(row0 >> 11);
            const int tl = (int)(row0 & 2047);
            #pragma unroll
            for (int r = 0; r < ROWS; ++r)
                vt[((size_t)b * HSn + h) * Tn + tl + r] = f2bf_rne(acc[r]);
        }
    }
}

// ---------------- MFMA flash attention ----------------
// 512 blocks x 4 waves. Block owns 16 q rows; waves split s-tiles (stride 4),
// independent online softmax, merged through LDS at the end.
// LDS (53 KB): per-wave swizzled Khi/Klo (4KB each), Vt (4KB), P (1KB);
// O/ml merge buffers alias the Khi/Klo regions (only used after the loop).
#define SM_KH 0
#define SM_KL 16384
#define SM_VT 32768
#define SM_PB 49152
#define SM_TOT 53248

__global__ __launch_bounds__(256) void attn_kernel(
    const u16* __restrict__ qh8, const u16* __restrict__ ql8,
    const u16* __restrict__ kh, const u16* __restrict__ kl,
    const u16* __restrict__ vt, float* __restrict__ out)
{
    __shared__ __align__(16) unsigned char smem[SM_TOT];
    const int tid  = threadIdx.x;
    const int wave = tid >> 6, lane = tid & 63;
    const int lo4  = lane & 15, g = lane >> 4;

    // load-balanced (batch, t-block) mapping: CU c gets tb and 127-tb
    const int sblk = blockIdx.x >> 8, c = blockIdx.x & 255;
    const int tb = sblk ? 127 - (c >> 1) : (c >> 1);
    const int b  = 2 * sblk + (c & 1);
    const int t0 = tb * 16;

    const u16* qhp = qh8 + ((size_t)b * Tn + t0) * HSn;
    const u16* qlp = ql8 + ((size_t)b * Tn + t0) * HSn;
    const u16* khp = kh + (size_t)b * Tn * HSn;
    const u16* klp = kl + (size_t)b * Tn * HSn;
    const u16* vtp = vt + (size_t)b * HSn * Tn;

    // A-fragments of q (row = lane&15, k-chunk = (lane>>4)*8), 2 K-halves
    bf16x8 qfh[2], qfl[2];
    #pragma unroll
    for (int ch = 0; ch < 2; ++ch) {
        qfh[ch] = *(const bf16x8*)(qhp + lo4 * HSn + ch * 32 + g * 8);
        qfl[ch] = *(const bf16x8*)(qlp + lo4 * HSn + ch * 32 + g * 8);
    }

    f32x4 O[4];
    #pragma unroll
    for (int n = 0; n < 4; ++n) O[n] = (f32x4){0.f, 0.f, 0.f, 0.f};
    float mrow[4], lrow[4];
    #pragma unroll
    for (int r = 0; r < 4; ++r) { mrow[r] = -1e30f; lrow[r] = 0.f; }

    const int nt = (t0 + 15) / 32 + 1;

    unsigned char* myKH = smem + SM_KH + wave * 4096;
    unsigned char* myKL = smem + SM_KL + wave * 4096;
    unsigned char* myVT = smem + SM_VT + wave * 4096;
    unsigned char* myPB = smem + SM_PB + wave * 1024;

    uint4 st[12];

    #define GLOAD(J)                                                          \
        {                                                                     \
            const int s0_ = (J) * 32;                                         \
            _Pragma("unroll")                                                 \
            for (int i = 0; i < 4; ++i) {                                     \
                int cc = i * 64 + lane;                                       \
                int ss = cc >> 3, hq = cc & 7;                                \
                st[i]     = *(const uint4*)(khp + (size_t)(s0_ + ss) * 64 + hq * 8); \
                st[4 + i] = *(const uint4*)(klp + (size_t)(s0_ + ss) * 64 + hq * 8); \
            }                                                                 \
            _Pragma("unroll")                                                 \
            for (int i = 0; i < 4; ++i) {                                     \
                int cc = i * 64 + lane;                                       \
                int hh = cc >> 2, sc = cc & 3;                                \
                st[8 + i] = *(const uint4*)(vtp + (size_t)hh * Tn + s0_ + sc * 8); \
            }                                                                 \
        }

    int j = wave;
    if (j < nt) GLOAD(j)
    for (; j < nt; j += 4) {
        // stage to swizzled LDS (XOR bits 4-5 of within-row byte offset)
        #pragma unroll
        for (int i = 0; i < 4; ++i) {
            int cc = i * 64 + lane;
            int ss = cc >> 3, hq = cc & 7;
            int koff = ss * 128 + ((hq * 16) ^ ((ss & 7) << 4));
            *(uint4*)(myKH + koff) = st[i];
            *(uint4*)(myKL + koff) = st[4 + i];
            int hh = cc >> 2, sc = cc & 3;
            int voff = hh * 64 + ((sc * 16) ^ ((hh & 3) << 4));
            *(uint4*)(myVT + voff) = st[8 + i];
        }
        const int s0 = j * 32;
        if (j + 4 < nt) GLOAD(j + 4)   // prefetch next tile during compute

        // QK^T: S(16x32) via bf16x2 emulation (hh + hl + lh)
        f32x4 accS[2];
        #pragma unroll
        for (int sb = 0; sb < 2; ++sb) {
            const int srow = sb * 16 + lo4;
            const int rswz = (srow & 7) << 4;
            bf16x8 k_h0 = *(const bf16x8*)(myKH + srow * 128 + ((16 * (0 + g)) ^ rswz));
            bf16x8 k_h1 = *(const bf16x8*)(myKH + srow * 128 + ((16 * (4 + g)) ^ rswz));
            bf16x8 k_l0 = *(const bf16x8*)(myKL + srow * 128 + ((16 * (0 + g)) ^ rswz));
            bf16x8 k_l1 = *(const bf16x8*)(myKL + srow * 128 + ((16 * (4 + g)) ^ rswz));
            f32x4 a = (f32x4){0.f, 0.f, 0.f, 0.f};
            a = __builtin_amdgcn_mfma_f32_16x16x32_bf16(qfh[0], k_h0, a, 0, 0, 0);
            a = __builtin_amdgcn_mfma_f32_16x16x32_bf16(qfh[1], k_h1, a, 0, 0, 0);
            a = __builtin_amdgcn_mfma_f32_16x16x32_bf16(qfl[0], k_h0, a, 0, 0, 0);
            a = __builtin_amdgcn_mfma_f32_16x16x32_bf16(qfl[1], k_h1, a, 0, 0, 0);
            a = __builtin_amdgcn_mfma_f32_16x16x32_bf16(qfh[0], k_l0, a, 0, 0, 0);
            a = __builtin_amdgcn_mfma_f32_16x16x32_bf16(qfh[1], k_l1, a, 0, 0, 0);
            accS[sb] = a;
        }

        // online softmax per output row (C layout: col=lane&15, row=g*4+reg)
        #pragma unroll
        for (int reg = 0; reg < 4; ++reg) {
            const int tg  = t0 + g * 4 + reg;
            const int sg0 = s0 + lo4;
            const int sg1 = s0 + 16 + lo4;
            float v0 = (sg0 <= tg) ? accS[0][reg] : -1e30f;
            float v1 = (sg1 <= tg) ? accS[1][reg] : -1e30f;
            float mt = fmaxf(v0, v1);
            mt = fmaxf(mt, __shfl_xor(mt, 1));
            mt = fmaxf(mt, __shfl_xor(mt, 2));
            mt = fmaxf(mt, __shfl_xor(mt, 4));
            mt = fmaxf(mt, __shfl_xor(mt, 8));
            float mn = fmaxf(mrow[reg], mt);
            float p0 = (sg0 <= tg) ? __expf(v0 - mn) : 0.f;  // explicit zero: robust for fully-masked rows
            float p1 = (sg1 <= tg) ? __expf(v1 - mn) : 0.f;
            float ps = p0 + p1;
            ps += __shfl_xor(ps, 1);
            ps += __shfl_xor(ps, 2);
            ps += __shfl_xor(ps, 4);
            ps += __shfl_xor(ps, 8);
            float alpha = __expf(mrow[reg] - mn);
            lrow[reg] = lrow[reg] * alpha + ps;
            mrow[reg] = mn;
            #pragma unroll
            for (int n = 0; n < 4; ++n) O[n][reg] *= alpha;
            // P -> LDS (bf16), swizzle key = row&3 = reg
            const int irow = g * 4 + reg;
            *(u16*)(myPB + ((irow * 64 + lo4 * 2) ^ (reg << 4)))      = f2bf_rne(p0);
            *(u16*)(myPB + ((irow * 64 + 32 + lo4 * 2) ^ (reg << 4))) = f2bf_rne(p1);
        }

        // PV: O(16x64) += P(16x32) @ V(32x64)
        bf16x8 pf = *(const bf16x8*)(myPB + ((lo4 * 64 + 16 * g) ^ ((lo4 & 3) << 4)));
        #pragma unroll
        for (int n = 0; n < 4; ++n) {
            const int hrow = n * 16 + lo4;
            bf16x8 vf = *(const bf16x8*)(myVT + ((hrow * 64 + 16 * g) ^ ((hrow & 3) << 4)));
            O[n] = __builtin_amdgcn_mfma_f32_16x16x32_bf16(pf, vf, O[n], 0, 0, 0);
        }
    }

    // write per-wave partials (alias KH/KL regions — safe after loop)
    float* om = (float*)(smem + SM_KH + wave * 4096);   // 16x64 f32
    float* ml = (float*)(smem + SM_KL + wave * 4096);   // 16x{m,l}
    #pragma unroll
    for (int n = 0; n < 4; ++n)
        #pragma unroll
        for (int reg = 0; reg < 4; ++reg)
            om[(g * 4 + reg) * 64 + n * 16 + lo4] = O[n][reg];
    if (lo4 == 0) {
        #pragma unroll
        for (int reg = 0; reg < 4; ++reg) {
            ml[(g * 4 + reg) * 2 + 0] = mrow[reg];
            ml[(g * 4 + reg) * 2 + 1] = lrow[reg];
        }
    }
    __syncthreads();

    // merge 4 partials: thread -> (row r, 4 h's)
    const int r  = tid >> 4;
    const int h4 = (tid & 15) * 4;
    float mw[4], lw[4], mstar = -1e30f;
    #pragma unroll
    for (int w = 0; w < 4; ++w) {
        const float* mlw = (const float*)(smem + SM_KL + w * 4096);
        mw[w] = mlw[r * 2 + 0];
        lw[w] = mlw[r * 2 + 1];
        mstar = fmaxf(mstar, mw[w]);
    }
    float lstar = 0.f, ew[4];
    #pragma unroll
    for (int w = 0; w < 4; ++w) { ew[w] = __expf(mw[w] - mstar); lstar += lw[w] * ew[w]; }
    float4 a4 = {0.f, 0.f, 0.f, 0.f};
    #pragma unroll
    for (int w = 0; w < 4; ++w) {
        const float* omw = (const float*)(smem + SM_KH + w * 4096);
        float4 t4 = *(const float4*)(omw + r * 64 + h4);
        a4.x += t4.x * ew[w]; a4.y += t4.y * ew[w];
        a4.z += t4.z * ew[w]; a4.w += t4.w * ew[w];
    }
    const float inv = 1.f / lstar;
    a4.x *= inv; a4.y *= inv; a4.z *= inv; a4.w *= inv;
    *(float4*)(out + ((size_t)b * Tn + t0 + r) * HSn + h4) = a4;
}

extern "C" void kernel_launch(void* const* d_in, const int* in_sizes, int n_in,
                              void* d_out, int out_size, void* d_ws, size_t ws_size,
                              hipStream_t stream) {
    const float* x  = (const float*)d_in[0];
    const float* Wk = (const float*)d_in[1];
    const float* Wq = (const float*)d_in[2];
    const float* Wv = (const float*)d_in[3];
    float* out = (float*)d_out;

    const size_t per = (size_t)Bn * Tn * HSn;   // 524288
    u16* qh8 = (u16*)d_ws;
    u16* ql8 = qh8 + per;
    u16* khw = ql8 + per;
    u16* klw = khw + per;
    u16* vtw = klw + per;

    hipLaunchKernelGGL(proj_kernel, dim3(Bn * Tn / ROWS), dim3(256), 0, stream,
                       x, Wk, Wq, Wv, qh8, ql8, khw, klw, vtw);
    hipLaunchKernelGGL(attn_kernel, dim3(512), dim3(256), 0, stream,
                       qh8, ql8, khw, klw, vtw, out);
}

// Round 4
// 98.514 us; speedup vs baseline: 2.9283x; 1.3930x over previous
//
#include <hip/hip_runtime.h>

#define Bn 4
#define Tn 2048
#define Dn 1024
#define HSn 64

typedef __attribute__((ext_vector_type(8))) short bf16x8;
typedef __attribute__((ext_vector_type(4))) float f32x4;
typedef __attribute__((ext_vector_type(4))) short s16x4;
typedef unsigned short u16;
typedef unsigned int u32;

__device__ __forceinline__ u16 f2bf_rne(float x) {
    u32 u = __float_as_uint(x);
    return (u16)((u + 0x7FFFu + ((u >> 16) & 1u)) >> 16);
}
__device__ __forceinline__ u16 f2bf_trunc(float x) {
    return (u16)(__float_as_uint(x) >> 16);
}
__device__ __forceinline__ float bf2f(u16 h) {
    return __uint_as_float(((u32)h) << 16);
}

#define GLL16(g, l)                                                        \
    __builtin_amdgcn_global_load_lds(                                      \
        (const __attribute__((address_space(1))) void*)(g),                \
        (__attribute__((address_space(3))) void*)(l), 16, 0, 0)

// ---------------- Prep: W^T hi/lo bf16, packed per k-step ----------------
// wtp[n][ks][0:32]=hi bf16, [32:64]=lo bf16  (n: 0-63 Wk, 64-127 Wq*8, 128-191 Wv)
__global__ __launch_bounds__(256) void wprep_kernel(
    const float* __restrict__ Wk, const float* __restrict__ Wq,
    const float* __restrict__ Wv, u16* __restrict__ wtp)
{
    __shared__ float ws_[64][65];
    const int kb = blockIdx.x;        // k-tile of 64
    const int w  = blockIdx.y;        // 0=Wk,1=Wq,2=Wv
    const float* __restrict__ W = (w == 0) ? Wk : (w == 1) ? Wq : Wv;
    const float scale = (w == 1) ? 8.0f : 1.0f;   // fold *sqrt(HS) into Wq
    const int t = threadIdx.x;

    {
        const int kl = t >> 2, hq = t & 3;
        #pragma unroll
        for (int i = 0; i < 4; ++i) {
            float4 f = *(const float4*)(W + (size_t)(kb * 64 + kl) * 64 + hq * 16 + i * 4);
            ws_[kl][hq * 16 + i * 4 + 0] = f.x; ws_[kl][hq * 16 + i * 4 + 1] = f.y;
            ws_[kl][hq * 16 + i * 4 + 2] = f.z; ws_[kl][hq * 16 + i * 4 + 3] = f.w;
        }
    }
    __syncthreads();

    const int h = t & 63, quarter = t >> 6;
    const int n = w * 64 + h;
    const int ks = kb * 2 + (quarter >> 1);
    const int k_in0 = (quarter & 1) * 16;
    u16 hib[16], lob[16];
    #pragma unroll
    for (int j = 0; j < 16; ++j) {
        float v = ws_[quarter * 16 + j][h] * scale;
        u16 hi = f2bf_trunc(v);
        hib[j] = hi;
        lob[j] = f2bf_trunc(v - bf2f(hi));
    }
    u16* dst = wtp + (size_t)n * 2048 + ks * 64;
    *(uint4*)(dst + k_in0)          = *(const uint4*)&hib[0];
    *(uint4*)(dst + k_in0 + 8)      = *(const uint4*)&hib[8];
    *(uint4*)(dst + 32 + k_in0)     = *(const uint4*)&lob[0];
    *(uint4*)(dst + 32 + k_in0 + 8) = *(const uint4*)&lob[8];
}

// ---------------- Projection GEMM: [8192 x 1024] @ [1024 x 192] ----------------
// 256 blocks x 4 waves; block = 32 rows; wave = 1 row-tile(16) x 6 col-tiles(96).
// x fp32 and W^T hi/lo staged via global_load_lds (linear dest, pre-swizzled src).
#define NKS 32
#define XBUF(P) (smem + (P) * 4096)
#define BBUF(P) (smem + 8192 + (P) * 24576)

__global__ __launch_bounds__(256) void proj_gemm(
    const float* __restrict__ x, const u16* __restrict__ wtp,
    u16* __restrict__ qh8, u16* __restrict__ ql8,
    u16* __restrict__ kh,  u16* __restrict__ kl,
    u16* __restrict__ vt)
{
    __shared__ __align__(16) unsigned char smem[57344];  // x: 2*4KB, B: 2*24KB

    const int tid  = threadIdx.x;
    const int wave = tid >> 6, lane = tid & 63;
    const int lo4  = lane & 15, g = lane >> 4;
    const int row0 = blockIdx.x * 32;
    const int rt   = wave & 1;           // row-tile
    const int cbase = (wave >> 1) * 6;   // first col-tile
    const int rl = rt * 16 + lo4;        // local row for A-frag

    f32x4 acc[6];
    #pragma unroll
    for (int c = 0; c < 6; ++c) acc[c] = (f32x4){0.f, 0.f, 0.f, 0.f};

    // staging indices (content swizzled: physical chunk p holds logical p^(row&7))
    const int xr = tid >> 3, xc = tid & 7;
    const int xsw = (xc ^ (xr & 7)) << 2;          // fp32 elems within row
    const float* xsrc0 = x + (size_t)(row0 + xr) * Dn + xsw;

    #define STAGE(P, KS)                                                     \
        {                                                                    \
            GLL16(xsrc0 + (KS) * 32, XBUF(P) + tid * 16);                    \
            _Pragma("unroll")                                                \
            for (int i = 0; i < 6; ++i) {                                    \
                const int c = i * 256 + tid;                                 \
                const int n_ = c >> 3, p_ = c & 7;                           \
                const int l_ = p_ ^ (n_ & 7);                                \
                const u16* src = wtp + (size_t)n_ * 2048 + (KS) * 64         \
                                 + ((l_ & 3) << 3) + ((l_ >> 2) << 5);       \
                GLL16(src, BBUF(P) + c * 16);                                \
            }                                                                \
        }

    STAGE(0, 0)
    __syncthreads();
    int pb = 0;
    for (int ks = 0; ks < NKS; ++ks) {
        if (ks + 1 < NKS) STAGE(pb ^ 1, ks + 1)

        // A fragments: 8 fp32 -> hi/lo bf16x8
        bf16x8 ah, al;
        {
            const unsigned char* xb = XBUF(pb) + rl * 128;
            f32x4 f0 = *(const f32x4*)(xb + (((2 * g + 0) ^ (rl & 7)) << 4));
            f32x4 f1 = *(const f32x4*)(xb + (((2 * g + 1) ^ (rl & 7)) << 4));
            #pragma unroll
            for (int j = 0; j < 4; ++j) {
                u16 h0 = f2bf_trunc(f0[j]);
                ah[j] = (short)h0;
                al[j] = (short)f2bf_trunc(f0[j] - bf2f(h0));
                u16 h1 = f2bf_trunc(f1[j]);
                ah[4 + j] = (short)h1;
                al[4 + j] = (short)f2bf_trunc(f1[j] - bf2f(h1));
            }
        }
        // B fragments + MFMA (emu: xh*wh + xl*wh + xh*wl)
        #pragma unroll
        for (int ct = 0; ct < 6; ++ct) {
            const int n = (cbase + ct) * 16 + lo4;
            const unsigned char* bb = BBUF(pb) + n * 128;
            bf16x8 bh = *(const bf16x8*)(bb + (((g)     ^ (n & 7)) << 4));
            bf16x8 bl = *(const bf16x8*)(bb + (((4 + g) ^ (n & 7)) << 4));
            acc[ct] = __builtin_amdgcn_mfma_f32_16x16x32_bf16(ah, bh, acc[ct], 0, 0, 0);
            acc[ct] = __builtin_amdgcn_mfma_f32_16x16x32_bf16(al, bh, acc[ct], 0, 0, 0);
            acc[ct] = __builtin_amdgcn_mfma_f32_16x16x32_bf16(ah, bl, acc[ct], 0, 0, 0);
        }
        __syncthreads();
        pb ^= 1;
    }

    // epilogue: C layout col=lane&15, row=g*4+reg
    const int grow = row0 + rt * 16 + g * 4;
    #pragma unroll
    for (int ct = 0; ct < 6; ++ct) {
        const int n = (cbase + ct) * 16 + lo4;
        if (n < 64) {
            #pragma unroll
            for (int reg = 0; reg < 4; ++reg) {
                float v = acc[ct][reg];
                u16 hi = f2bf_trunc(v);
                kh[(size_t)(grow + reg) * HSn + n] = hi;
                kl[(size_t)(grow + reg) * HSn + n] = f2bf_trunc(v - bf2f(hi));
            }
        } else if (n < 128) {
            #pragma unroll
            for (int reg = 0; reg < 4; ++reg) {
                float v = acc[ct][reg];   // already *8 (folded into Wq)
                u16 hi = f2bf_trunc(v);
                qh8[(size_t)(grow + reg) * HSn + (n - 64)] = hi;
                ql8[(size_t)(grow + reg) * HSn + (n - 64)] = f2bf_trunc(v - bf2f(hi));
            }
        } else {
            s16x4 pack;
            #pragma unroll
            for (int reg = 0; reg < 4; ++reg)
                pack[reg] = (short)f2bf_rne(acc[ct][reg]);
            const int b = grow >> 11, tl = grow & 2047;
            *(s16x4*)(vt + ((size_t)b * HSn + (n - 128)) * Tn + tl) = pack;
        }
    }
}

// ---------------- MFMA flash attention (unchanged) ----------------
#define SM_KH 0
#define SM_KL 16384
#define SM_VT 32768
#define SM_PB 49152
#define SM_TOT 53248

__global__ __launch_bounds__(256) void attn_kernel(
    const u16* __restrict__ qh8, const u16* __restrict__ ql8,
    const u16* __restrict__ kh, const u16* __restrict__ kl,
    const u16* __restrict__ vt, float* __restrict__ out)
{
    __shared__ __align__(16) unsigned char smem[SM_TOT];
    const int tid  = threadIdx.x;
    const int wave = tid >> 6, lane = tid & 63;
    const int lo4  = lane & 15, g = lane >> 4;

    const int sblk = blockIdx.x >> 8, c = blockIdx.x & 255;
    const int tb = sblk ? 127 - (c >> 1) : (c >> 1);
    const int b  = 2 * sblk + (c & 1);
    const int t0 = tb * 16;

    const u16* qhp = qh8 + ((size_t)b * Tn + t0) * HSn;
    const u16* qlp = ql8 + ((size_t)b * Tn + t0) * HSn;
    const u16* khp = kh + (size_t)b * Tn * HSn;
    const u16* klp = kl + (size_t)b * Tn * HSn;
    const u16* vtp = vt + (size_t)b * HSn * Tn;

    bf16x8 qfh[2], qfl[2];
    #pragma unroll
    for (int ch = 0; ch < 2; ++ch) {
        qfh[ch] = *(const bf16x8*)(qhp + lo4 * HSn + ch * 32 + g * 8);
        qfl[ch] = *(const bf16x8*)(qlp + lo4 * HSn + ch * 32 + g * 8);
    }

    f32x4 O[4];
    #pragma unroll
    for (int n = 0; n < 4; ++n) O[n] = (f32x4){0.f, 0.f, 0.f, 0.f};
    float mrow[4], lrow[4];
    #pragma unroll
    for (int r = 0; r < 4; ++r) { mrow[r] = -1e30f; lrow[r] = 0.f; }

    const int nt = (t0 + 15) / 32 + 1;

    unsigned char* myKH = smem + SM_KH + wave * 4096;
    unsigned char* myKL = smem + SM_KL + wave * 4096;
    unsigned char* myVT = smem + SM_VT + wave * 4096;
    unsigned char* myPB = smem + SM_PB + wave * 1024;

    uint4 st[12];

    #define GLOAD(J)                                                          \
        {                                                                     \
            const int s0_ = (J) * 32;                                         \
            _Pragma("unroll")                                                 \
            for (int i = 0; i < 4; ++i) {                                     \
                int cc = i * 64 + lane;                                       \
                int ss = cc >> 3, hq = cc & 7;                                \
                st[i]     = *(const uint4*)(khp + (size_t)(s0_ + ss) * 64 + hq * 8); \
                st[4 + i] = *(const uint4*)(klp + (size_t)(s0_ + ss) * 64 + hq * 8); \
            }                                                                 \
            _Pragma("unroll")                                                 \
            for (int i = 0; i < 4; ++i) {                                     \
                int cc = i * 64 + lane;                                       \
                int hh = cc >> 2, sc = cc & 3;                                \
                st[8 + i] = *(const uint4*)(vtp + (size_t)hh * Tn + s0_ + sc * 8); \
            }                                                                 \
        }

    int j = wave;
    if (j < nt) GLOAD(j)
    for (; j < nt; j += 4) {
        #pragma unroll
        for (int i = 0; i < 4; ++i) {
            int cc = i * 64 + lane;
            int ss = cc >> 3, hq = cc & 7;
            int koff = ss * 128 + ((hq * 16) ^ ((ss & 7) << 4));
            *(uint4*)(myKH + koff) = st[i];
            *(uint4*)(myKL + koff) = st[4 + i];
            int hh = cc >> 2, sc = cc & 3;
            int voff = hh * 64 + ((sc * 16) ^ ((hh & 3) << 4));
            *(uint4*)(myVT + voff) = st[8 + i];
        }
        const int s0 = j * 32;
        if (j + 4 < nt) GLOAD(j + 4)

        f32x4 accS[2];
        #pragma unroll
        for (int sb = 0; sb < 2; ++sb) {
            const int srow = sb * 16 + lo4;
            const int rswz = (srow & 7) << 4;
            bf16x8 k_h0 = *(const bf16x8*)(myKH + srow * 128 + ((16 * (0 + g)) ^ rswz));
            bf16x8 k_h1 = *(const bf16x8*)(myKH + srow * 128 + ((16 * (4 + g)) ^ rswz));
            bf16x8 k_l0 = *(const bf16x8*)(myKL + srow * 128 + ((16 * (0 + g)) ^ rswz));
            bf16x8 k_l1 = *(const bf16x8*)(myKL + srow * 128 + ((16 * (4 + g)) ^ rswz));
            f32x4 a = (f32x4){0.f, 0.f, 0.f, 0.f};
            a = __builtin_amdgcn_mfma_f32_16x16x32_bf16(qfh[0], k_h0, a, 0, 0, 0);
            a = __builtin_amdgcn_mfma_f32_16x16x32_bf16(qfh[1], k_h1, a, 0, 0, 0);
            a = __builtin_amdgcn_mfma_f32_16x16x32_bf16(qfl[0], k_h0, a, 0, 0, 0);
            a = __builtin_amdgcn_mfma_f32_16x16x32_bf16(qfl[1], k_h1, a, 0, 0, 0);
            a = __builtin_amdgcn_mfma_f32_16x16x32_bf16(qfh[0], k_l0, a, 0, 0, 0);
            a = __builtin_amdgcn_mfma_f32_16x16x32_bf16(qfh[1], k_l1, a, 0, 0, 0);
            accS[sb] = a;
        }

        #pragma unroll
        for (int reg = 0; reg < 4; ++reg) {
            const int tg  = t0 + g * 4 + reg;
            const int sg0 = s0 + lo4;
            const int sg1 = s0 + 16 + lo4;
            float v0 = (sg0 <= tg) ? accS[0][reg] : -1e30f;
            float v1 = (sg1 <= tg) ? accS[1][reg] : -1e30f;
            float mt = fmaxf(v0, v1);
            mt = fmaxf(mt, __shfl_xor(mt, 1));
            mt = fmaxf(mt, __shfl_xor(mt, 2));
            mt = fmaxf(mt, __shfl_xor(mt, 4));
            mt = fmaxf(mt, __shfl_xor(mt, 8));
            float mn = fmaxf(mrow[reg], mt);
            float p0 = (sg0 <= tg) ? __expf(v0 - mn) : 0.f;
            float p1 = (sg1 <= tg) ? __expf(v1 - mn) : 0.f;
            float ps = p0 + p1;
            ps += __shfl_xor(ps, 1);
            ps += __shfl_xor(ps, 2);
            ps += __shfl_xor(ps, 4);
            ps += __shfl_xor(ps, 8);
            float alpha = __expf(mrow[reg] - mn);
            lrow[reg] = lrow[reg] * alpha + ps;
            mrow[reg] = mn;
            #pragma unroll
            for (int n = 0; n < 4; ++n) O[n][reg] *= alpha;
            const int irow = g * 4 + reg;
            *(u16*)(myPB + ((irow * 64 + lo4 * 2) ^ (reg << 4)))      = f2bf_rne(p0);
            *(u16*)(myPB + ((irow * 64 + 32 + lo4 * 2) ^ (reg << 4))) = f2bf_rne(p1);
        }

        bf16x8 pf = *(const bf16x8*)(myPB + ((lo4 * 64 + 16 * g) ^ ((lo4 & 3) << 4)));
        #pragma unroll
        for (int n = 0; n < 4; ++n) {
            const int hrow = n * 16 + lo4;
            bf16x8 vf = *(const bf16x8*)(myVT + ((hrow * 64 + 16 * g) ^ ((hrow & 3) << 4)));
            O[n] = __builtin_amdgcn_mfma_f32_16x16x32_bf16(pf, vf, O[n], 0, 0, 0);
        }
    }

    float* om = (float*)(smem + SM_KH + wave * 4096);
    float* ml = (float*)(smem + SM_KL + wave * 4096);
    #pragma unroll
    for (int n = 0; n < 4; ++n)
        #pragma unroll
        for (int reg = 0; reg < 4; ++reg)
            om[(g * 4 + reg) * 64 + n * 16 + lo4] = O[n][reg];
    if (lo4 == 0) {
        #pragma unroll
        for (int reg = 0; reg < 4; ++reg) {
            ml[(g * 4 + reg) * 2 + 0] = mrow[reg];
            ml[(g * 4 + reg) * 2 + 1] = lrow[reg];
        }
    }
    __syncthreads();

    const int r  = tid >> 4;
    const int h4 = (tid & 15) * 4;
    float mw[4], lw[4], mstar = -1e30f;
    #pragma unroll
    for (int w = 0; w < 4; ++w) {
        const float* mlw = (const float*)(smem + SM_KL + w * 4096);
        mw[w] = mlw[r * 2 + 0];
        lw[w] = mlw[r * 2 + 1];
        mstar = fmaxf(mstar, mw[w]);
    }
    float lstar = 0.f, ew[4];
    #pragma unroll
    for (int w = 0; w < 4; ++w) { ew[w] = __expf(mw[w] - mstar); lstar += lw[w] * ew[w]; }
    float4 a4 = {0.f, 0.f, 0.f, 0.f};
    #pragma unroll
    for (int w = 0; w < 4; ++w) {
        const float* omw = (const float*)(smem + SM_KH + w * 4096);
        float4 t4 = *(const float4*)(omw + r * 64 + h4);
        a4.x += t4.x * ew[w]; a4.y += t4.y * ew[w];
        a4.z += t4.z * ew[w]; a4.w += t4.w * ew[w];
    }
    const float inv = 1.f / lstar;
    a4.x *= inv; a4.y *= inv; a4.z *= inv; a4.w *= inv;
    *(float4*)(out + ((size_t)b * Tn + t0 + r) * HSn + h4) = a4;
}

extern "C" void kernel_launch(void* const* d_in, const int* in_sizes, int n_in,
                              void* d_out, int out_size, void* d_ws, size_t ws_size,
                              hipStream_t stream) {
    const float* x  = (const float*)d_in[0];
    const float* Wk = (const float*)d_in[1];
    const float* Wq = (const float*)d_in[2];
    const float* Wv = (const float*)d_in[3];
    float* out = (float*)d_out;

    const size_t per = (size_t)Bn * Tn * HSn;   // 524288
    u16* qh8 = (u16*)d_ws;
    u16* ql8 = qh8 + per;
    u16* khw = ql8 + per;
    u16* klw = khw + per;
    u16* vtw = klw + per;
    u16* wtp = vtw + per;                       // 192*2048 u16 = 768 KB

    hipLaunchKernelGGL(wprep_kernel, dim3(16, 3), dim3(256), 0, stream,
                       Wk, Wq, Wv, wtp);
    hipLaunchKernelGGL(proj_gemm, dim3(256), dim3(256), 0, stream,
                       x, wtp, qh8, ql8, khw, klw, vtw);
    hipLaunchKernelGGL(attn_kernel, dim3(512), dim3(256), 0, stream,
                       qh8, ql8, khw, klw, vtw, out);
}

// Round 5
// 67.430 us; speedup vs baseline: 4.2782x; 1.4610x over previous
//
#include <hip/hip_runtime.h>

#define Bn 4
#define Tn 2048
#define Dn 1024
#define HSn 64

typedef __attribute__((ext_vector_type(8))) short bf16x8;
typedef __attribute__((ext_vector_type(4))) float f32x4;
typedef __attribute__((ext_vector_type(4))) short s16x4;
typedef unsigned short u16;
typedef unsigned int u32;

__device__ __forceinline__ u16 f2bf_rne(float x) {
    u32 u = __float_as_uint(x);
    return (u16)((u + 0x7FFFu + ((u >> 16) & 1u)) >> 16);
}
__device__ __forceinline__ u16 f2bf_trunc(float x) {
    return (u16)(__float_as_uint(x) >> 16);
}
__device__ __forceinline__ float bf2f(u16 h) {
    return __uint_as_float(((u32)h) << 16);
}

#define GLL16(g, l)                                                        \
    __builtin_amdgcn_global_load_lds(                                      \
        (const __attribute__((address_space(1))) void*)(g),                \
        (__attribute__((address_space(3))) void*)(l), 16, 0, 0)

// ---------------- Prep: W^T hi/lo bf16, packed per k-step ----------------
// wtp[n][ks][0:32]=hi bf16, [32:64]=lo bf16  (n: 0-63 Wk, 64-127 Wq*8, 128-191 Wv)
__global__ __launch_bounds__(256) void wprep_kernel(
    const float* __restrict__ Wk, const float* __restrict__ Wq,
    const float* __restrict__ Wv, u16* __restrict__ wtp)
{
    __shared__ float ws_[64][65];
    const int kb = blockIdx.x;        // k-tile of 64
    const int w  = blockIdx.y;        // 0=Wk,1=Wq,2=Wv
    const float* __restrict__ W = (w == 0) ? Wk : (w == 1) ? Wq : Wv;
    const float scale = (w == 1) ? 8.0f : 1.0f;   // fold *sqrt(HS) into Wq
    const int t = threadIdx.x;

    {
        const int kl = t >> 2, hq = t & 3;
        #pragma unroll
        for (int i = 0; i < 4; ++i) {
            float4 f = *(const float4*)(W + (size_t)(kb * 64 + kl) * 64 + hq * 16 + i * 4);
            ws_[kl][hq * 16 + i * 4 + 0] = f.x; ws_[kl][hq * 16 + i * 4 + 1] = f.y;
            ws_[kl][hq * 16 + i * 4 + 2] = f.z; ws_[kl][hq * 16 + i * 4 + 3] = f.w;
        }
    }
    __syncthreads();

    const int h = t & 63, quarter = t >> 6;
    const int n = w * 64 + h;
    const int ks = kb * 2 + (quarter >> 1);
    const int k_in0 = (quarter & 1) * 16;
    u16 hib[16], lob[16];
    #pragma unroll
    for (int j = 0; j < 16; ++j) {
        float v = ws_[quarter * 16 + j][h] * scale;
        u16 hi = f2bf_trunc(v);
        hib[j] = hi;
        lob[j] = f2bf_trunc(v - bf2f(hi));
    }
    u16* dst = wtp + (size_t)n * 2048 + ks * 64;
    *(uint4*)(dst + k_in0)          = *(const uint4*)&hib[0];
    *(uint4*)(dst + k_in0 + 8)      = *(const uint4*)&hib[8];
    *(uint4*)(dst + 32 + k_in0)     = *(const uint4*)&lob[0];
    *(uint4*)(dst + 32 + k_in0 + 8) = *(const uint4*)&lob[8];
}

// ---------------- Projection GEMM: [8192 x 1024] @ [1024 x 192] ----------------
#define NKS 32
#define XBUF(P) (smem + (P) * 4096)
#define BBUF(P) (smem + 8192 + (P) * 24576)

__global__ __launch_bounds__(256) void proj_gemm(
    const float* __restrict__ x, const u16* __restrict__ wtp,
    u16* __restrict__ qh8, u16* __restrict__ ql8,
    u16* __restrict__ kh,  u16* __restrict__ kl,
    u16* __restrict__ vt)
{
    __shared__ __align__(16) unsigned char smem[57344];  // x: 2*4KB, B: 2*24KB

    const int tid  = threadIdx.x;
    const int wave = tid >> 6, lane = tid & 63;
    const int lo4  = lane & 15, g = lane >> 4;
    const int row0 = blockIdx.x * 32;
    const int rt   = wave & 1;           // row-tile
    const int cbase = (wave >> 1) * 6;   // first col-tile
    const int rl = rt * 16 + lo4;        // local row for A-frag

    f32x4 acc[6];
    #pragma unroll
    for (int c = 0; c < 6; ++c) acc[c] = (f32x4){0.f, 0.f, 0.f, 0.f};

    const int xr = tid >> 3, xc = tid & 7;
    const int xsw = (xc ^ (xr & 7)) << 2;
    const float* xsrc0 = x + (size_t)(row0 + xr) * Dn + xsw;

    #define STAGE(P, KS)                                                     \
        {                                                                    \
            GLL16(xsrc0 + (KS) * 32, XBUF(P) + tid * 16);                    \
            _Pragma("unroll")                                                \
            for (int i = 0; i < 6; ++i) {                                    \
                const int c = i * 256 + tid;                                 \
                const int n_ = c >> 3, p_ = c & 7;                           \
                const int l_ = p_ ^ (n_ & 7);                                \
                const u16* src = wtp + (size_t)n_ * 2048 + (KS) * 64         \
                                 + ((l_ & 3) << 3) + ((l_ >> 2) << 5);       \
                GLL16(src, BBUF(P) + c * 16);                                \
            }                                                                \
        }

    STAGE(0, 0)
    __syncthreads();
    int pb = 0;
    for (int ks = 0; ks < NKS; ++ks) {
        if (ks + 1 < NKS) STAGE(pb ^ 1, ks + 1)

        bf16x8 ah, al;
        {
            const unsigned char* xb = XBUF(pb) + rl * 128;
            f32x4 f0 = *(const f32x4*)(xb + (((2 * g + 0) ^ (rl & 7)) << 4));
            f32x4 f1 = *(const f32x4*)(xb + (((2 * g + 1) ^ (rl & 7)) << 4));
            #pragma unroll
            for (int j = 0; j < 4; ++j) {
                u16 h0 = f2bf_trunc(f0[j]);
                ah[j] = (short)h0;
                al[j] = (short)f2bf_trunc(f0[j] - bf2f(h0));
                u16 h1 = f2bf_trunc(f1[j]);
                ah[4 + j] = (short)h1;
                al[4 + j] = (short)f2bf_trunc(f1[j] - bf2f(h1));
            }
        }
        #pragma unroll
        for (int ct = 0; ct < 6; ++ct) {
            const int n = (cbase + ct) * 16 + lo4;
            const unsigned char* bb = BBUF(pb) + n * 128;
            bf16x8 bh = *(const bf16x8*)(bb + (((g)     ^ (n & 7)) << 4));
            bf16x8 bl = *(const bf16x8*)(bb + (((4 + g) ^ (n & 7)) << 4));
            acc[ct] = __builtin_amdgcn_mfma_f32_16x16x32_bf16(ah, bh, acc[ct], 0, 0, 0);
            acc[ct] = __builtin_amdgcn_mfma_f32_16x16x32_bf16(al, bh, acc[ct], 0, 0, 0);
            acc[ct] = __builtin_amdgcn_mfma_f32_16x16x32_bf16(ah, bl, acc[ct], 0, 0, 0);
        }
        __syncthreads();
        pb ^= 1;
    }

    const int grow = row0 + rt * 16 + g * 4;
    #pragma unroll
    for (int ct = 0; ct < 6; ++ct) {
        const int n = (cbase + ct) * 16 + lo4;
        if (n < 64) {
            #pragma unroll
            for (int reg = 0; reg < 4; ++reg) {
                float v = acc[ct][reg];
                u16 hi = f2bf_trunc(v);
                kh[(size_t)(grow + reg) * HSn + n] = hi;
                kl[(size_t)(grow + reg) * HSn + n] = f2bf_trunc(v - bf2f(hi));
            }
        } else if (n < 128) {
            #pragma unroll
            for (int reg = 0; reg < 4; ++reg) {
                float v = acc[ct][reg];   // already *8 (folded into Wq)
                u16 hi = f2bf_trunc(v);
                qh8[(size_t)(grow + reg) * HSn + (n - 64)] = hi;
                ql8[(size_t)(grow + reg) * HSn + (n - 64)] = f2bf_trunc(v - bf2f(hi));
            }
        } else {
            s16x4 pack;
            #pragma unroll
            for (int reg = 0; reg < 4; ++reg)
                pack[reg] = (short)f2bf_rne(acc[ct][reg]);
            const int b = grow >> 11, tl = grow & 2047;
            *(s16x4*)(vt + ((size_t)b * HSn + (n - 128)) * Tn + tl) = pack;
        }
    }
}

// ---------------- MFMA flash attention v2: reg-staged K/V, no spill ----------------
// 512 blocks x 4 waves; block = 16 q rows; wave w handles s-tiles w, w+4, ...
// K/V fragments loaded global->VGPR (L2-resident), double-buffered A/B sets.
// LDS: per-wave P buffer (1KB) + merge buffers only. No barriers in main loop.
struct KVset {
    bf16x8 kh0[2], kh1[2], kl0[2], kl1[2], vf[4];
};

__global__ __launch_bounds__(256, 2) void attn_kernel(
    const u16* __restrict__ qh8, const u16* __restrict__ ql8,
    const u16* __restrict__ kh, const u16* __restrict__ kl,
    const u16* __restrict__ vt, float* __restrict__ out)
{
    __shared__ __align__(16) unsigned char pbuf[4096];    // P: 4 waves x 1KB
    __shared__ __align__(16) float om_s[4][16][64];       // merge O
    __shared__ float ml_s[4][16][2];                      // merge m,l

    const int tid  = threadIdx.x;
    const int wave = tid >> 6, lane = tid & 63;
    const int lo4  = lane & 15, g = lane >> 4;

    const int sblk = blockIdx.x >> 8, c = blockIdx.x & 255;
    const int tb = sblk ? 127 - (c >> 1) : (c >> 1);
    const int b  = 2 * sblk + (c & 1);
    const int t0 = tb * 16;

    const u16* qhp = qh8 + ((size_t)b * Tn + t0) * HSn;
    const u16* qlp = ql8 + ((size_t)b * Tn + t0) * HSn;
    const u16* khp = kh + (size_t)b * Tn * HSn;
    const u16* klp = kl + (size_t)b * Tn * HSn;
    const u16* vtp = vt + (size_t)b * HSn * Tn;

    bf16x8 qfh[2], qfl[2];
    #pragma unroll
    for (int ch = 0; ch < 2; ++ch) {
        qfh[ch] = *(const bf16x8*)(qhp + lo4 * HSn + ch * 32 + g * 8);
        qfl[ch] = *(const bf16x8*)(qlp + lo4 * HSn + ch * 32 + g * 8);
    }

    f32x4 O[4];
    #pragma unroll
    for (int n = 0; n < 4; ++n) O[n] = (f32x4){0.f, 0.f, 0.f, 0.f};
    float mrow[4], lrow[4];
    #pragma unroll
    for (int r = 0; r < 4; ++r) { mrow[r] = -1e30f; lrow[r] = 0.f; }

    const int nt = (t0 + 15) / 32 + 1;
    unsigned char* myPB = pbuf + wave * 1024;

    #define LOADSET(S, J)                                                     \
        {                                                                     \
            const int s0_ = (J) * 32;                                         \
            _Pragma("unroll")                                                 \
            for (int sb = 0; sb < 2; ++sb) {                                  \
                const u16* kr = khp + (size_t)(s0_ + sb * 16 + lo4) * HSn;    \
                const u16* lr = klp + (size_t)(s0_ + sb * 16 + lo4) * HSn;    \
                S.kh0[sb] = *(const bf16x8*)(kr + g * 8);                     \
                S.kh1[sb] = *(const bf16x8*)(kr + 32 + g * 8);                \
                S.kl0[sb] = *(const bf16x8*)(lr + g * 8);                     \
                S.kl1[sb] = *(const bf16x8*)(lr + 32 + g * 8);                \
            }                                                                 \
            _Pragma("unroll")                                                 \
            for (int n = 0; n < 4; ++n)                                       \
                S.vf[n] = *(const bf16x8*)(vtp + (size_t)(n * 16 + lo4) * Tn  \
                                           + s0_ + g * 8);                    \
        }

    #define COMPUTE(S, J)                                                     \
        {                                                                     \
            const int s0 = (J) * 32;                                          \
            f32x4 accS[2];                                                    \
            __builtin_amdgcn_s_setprio(1);                                    \
            _Pragma("unroll")                                                 \
            for (int sb = 0; sb < 2; ++sb) {                                  \
                f32x4 a = (f32x4){0.f, 0.f, 0.f, 0.f};                        \
                a = __builtin_amdgcn_mfma_f32_16x16x32_bf16(qfh[0], S.kh0[sb], a, 0, 0, 0); \
                a = __builtin_amdgcn_mfma_f32_16x16x32_bf16(qfh[1], S.kh1[sb], a, 0, 0, 0); \
                a = __builtin_amdgcn_mfma_f32_16x16x32_bf16(qfl[0], S.kh0[sb], a, 0, 0, 0); \
                a = __builtin_amdgcn_mfma_f32_16x16x32_bf16(qfl[1], S.kh1[sb], a, 0, 0, 0); \
                a = __builtin_amdgcn_mfma_f32_16x16x32_bf16(qfh[0], S.kl0[sb], a, 0, 0, 0); \
                a = __builtin_amdgcn_mfma_f32_16x16x32_bf16(qfh[1], S.kl1[sb], a, 0, 0, 0); \
                accS[sb] = a;                                                 \
            }                                                                 \
            __builtin_amdgcn_s_setprio(0);                                    \
            _Pragma("unroll")                                                 \
            for (int reg = 0; reg < 4; ++reg) {                               \
                const int tg  = t0 + g * 4 + reg;                             \
                const int sg0 = s0 + lo4;                                     \
                const int sg1 = s0 + 16 + lo4;                                \
                float v0 = (sg0 <= tg) ? accS[0][reg] : -1e30f;               \
                float v1 = (sg1 <= tg) ? accS[1][reg] : -1e30f;               \
                float mt = fmaxf(v0, v1);                                     \
                mt = fmaxf(mt, __shfl_xor(mt, 1));                            \
                mt = fmaxf(mt, __shfl_xor(mt, 2));                            \
                mt = fmaxf(mt, __shfl_xor(mt, 4));                            \
                mt = fmaxf(mt, __shfl_xor(mt, 8));                            \
                float mn = fmaxf(mrow[reg], mt);                              \
                float p0 = (sg0 <= tg) ? __expf(v0 - mn) : 0.f;               \
                float p1 = (sg1 <= tg) ? __expf(v1 - mn) : 0.f;               \
                float ps = p0 + p1;                                           \
                ps += __shfl_xor(ps, 1);                                      \
                ps += __shfl_xor(ps, 2);                                      \
                ps += __shfl_xor(ps, 4);                                      \
                ps += __shfl_xor(ps, 8);                                      \
                float alpha = __expf(mrow[reg] - mn);                         \
                lrow[reg] = lrow[reg] * alpha + ps;                           \
                mrow[reg] = mn;                                               \
                _Pragma("unroll")                                             \
                for (int n = 0; n < 4; ++n) O[n][reg] *= alpha;               \
                const int irow = g * 4 + reg;                                 \
                *(u16*)(myPB + ((irow * 64 + lo4 * 2) ^ (reg << 4)))      = f2bf_rne(p0); \
                *(u16*)(myPB + ((irow * 64 + 32 + lo4 * 2) ^ (reg << 4))) = f2bf_rne(p1); \
            }                                                                 \
            bf16x8 pf = *(const bf16x8*)(myPB + ((lo4 * 64 + 16 * g) ^ ((lo4 & 3) << 4))); \
            __builtin_amdgcn_s_setprio(1);                                    \
            _Pragma("unroll")                                                 \
            for (int n = 0; n < 4; ++n)                                       \
                O[n] = __builtin_amdgcn_mfma_f32_16x16x32_bf16(pf, S.vf[n], O[n], 0, 0, 0); \
            __builtin_amdgcn_s_setprio(0);                                    \
        }

    KVset A, B;
    int j = wave;
    if (j < nt) LOADSET(A, j)
    while (j < nt) {
        if (j + 4 < nt) LOADSET(B, j + 4)
        COMPUTE(A, j)
        if (j + 4 < nt) {
            if (j + 8 < nt) LOADSET(A, j + 8)
            COMPUTE(B, j + 4)
        }
        j += 8;
    }

    // per-wave partials -> LDS
    #pragma unroll
    for (int n = 0; n < 4; ++n)
        #pragma unroll
        for (int reg = 0; reg < 4; ++reg)
            om_s[wave][g * 4 + reg][n * 16 + lo4] = O[n][reg];
    if (lo4 == 0) {
        #pragma unroll
        for (int reg = 0; reg < 4; ++reg) {
            ml_s[wave][g * 4 + reg][0] = mrow[reg];
            ml_s[wave][g * 4 + reg][1] = lrow[reg];
        }
    }
    __syncthreads();

    // merge 4 partials: thread -> (row r, 4 h's)
    const int r  = tid >> 4;
    const int h4 = (tid & 15) * 4;
    float mw[4], lw[4], mstar = -1e30f;
    #pragma unroll
    for (int w = 0; w < 4; ++w) {
        mw[w] = ml_s[w][r][0];
        lw[w] = ml_s[w][r][1];
        mstar = fmaxf(mstar, mw[w]);
    }
    float lstar = 0.f, ew[4];
    #pragma unroll
    for (int w = 0; w < 4; ++w) { ew[w] = __expf(mw[w] - mstar); lstar += lw[w] * ew[w]; }
    float4 a4 = {0.f, 0.f, 0.f, 0.f};
    #pragma unroll
    for (int w = 0; w < 4; ++w) {
        float4 t4 = *(const float4*)&om_s[w][r][h4];
        a4.x += t4.x * ew[w]; a4.y += t4.y * ew[w];
        a4.z += t4.z * ew[w]; a4.w += t4.w * ew[w];
    }
    const float inv = 1.f / lstar;
    a4.x *= inv; a4.y *= inv; a4.z *= inv; a4.w *= inv;
    *(float4*)(out + ((size_t)b * Tn + t0 + r) * HSn + h4) = a4;
}

extern "C" void kernel_launch(void* const* d_in, const int* in_sizes, int n_in,
                              void* d_out, int out_size, void* d_ws, size_t ws_size,
                              hipStream_t stream) {
    const float* x  = (const float*)d_in[0];
    const float* Wk = (const float*)d_in[1];
    const float* Wq = (const float*)d_in[2];
    const float* Wv = (const float*)d_in[3];
    float* out = (float*)d_out;

    const size_t per = (size_t)Bn * Tn * HSn;   // 524288
    u16* qh8 = (u16*)d_ws;
    u16* ql8 = qh8 + per;
    u16* khw = ql8 + per;
    u16* klw = khw + per;
    u16* vtw = klw + per;
    u16* wtp = vtw + per;                       // 192*2048 u16 = 768 KB

    hipLaunchKernelGGL(wprep_kernel, dim3(16, 3), dim3(256), 0, stream,
                       Wk, Wq, Wv, wtp);
    hipLaunchKernelGGL(proj_gemm, dim3(256), dim3(256), 0, stream,
                       x, wtp, qh8, ql8, khw, klw, vtw);
    hipLaunchKernelGGL(attn_kernel, dim3(512), dim3(256), 0, stream,
                       qh8, ql8, khw, klw, vtw, out);
}

// Round 6
// 59.678 us; speedup vs baseline: 4.8339x; 1.1299x over previous
//
#include <hip/hip_runtime.h>

#define Bn 4
#define Tn 2048
#define Dn 1024
#define HSn 64

typedef __attribute__((ext_vector_type(8))) short bf16x8;
typedef __attribute__((ext_vector_type(4))) float f32x4;
typedef __attribute__((ext_vector_type(4))) short s16x4;
typedef unsigned short u16;
typedef unsigned int u32;

__device__ __forceinline__ u16 f2bf_rne(float x) {
    u32 u = __float_as_uint(x);
    return (u16)((u + 0x7FFFu + ((u >> 16) & 1u)) >> 16);
}
__device__ __forceinline__ u16 f2bf_trunc(float x) {
    return (u16)(__float_as_uint(x) >> 16);
}
__device__ __forceinline__ float bf2f(u16 h) {
    return __uint_as_float(((u32)h) << 16);
}

#define GLL16(g, l)                                                        \
    __builtin_amdgcn_global_load_lds(                                      \
        (const __attribute__((address_space(1))) void*)(g),                \
        (__attribute__((address_space(3))) void*)(l), 16, 0, 0)

// ---------------- Prep: W^T hi/lo bf16, packed per k-step ----------------
// wtp[n][ks][0:32]=hi bf16, [32:64]=lo bf16  (n: 0-63 Wk, 64-127 Wq*8, 128-191 Wv)
__global__ __launch_bounds__(256) void wprep_kernel(
    const float* __restrict__ Wk, const float* __restrict__ Wq,
    const float* __restrict__ Wv, u16* __restrict__ wtp)
{
    __shared__ float ws_[64][65];
    const int kb = blockIdx.x;        // k-tile of 64
    const int w  = blockIdx.y;        // 0=Wk,1=Wq,2=Wv
    const float* __restrict__ W = (w == 0) ? Wk : (w == 1) ? Wq : Wv;
    const float scale = (w == 1) ? 8.0f : 1.0f;   // fold *sqrt(HS) into Wq
    const int t = threadIdx.x;

    {
        const int kl = t >> 2, hq = t & 3;
        #pragma unroll
        for (int i = 0; i < 4; ++i) {
            float4 f = *(const float4*)(W + (size_t)(kb * 64 + kl) * 64 + hq * 16 + i * 4);
            ws_[kl][hq * 16 + i * 4 + 0] = f.x; ws_[kl][hq * 16 + i * 4 + 1] = f.y;
            ws_[kl][hq * 16 + i * 4 + 2] = f.z; ws_[kl][hq * 16 + i * 4 + 3] = f.w;
        }
    }
    __syncthreads();

    const int h = t & 63, quarter = t >> 6;
    const int n = w * 64 + h;
    const int ks = kb * 2 + (quarter >> 1);
    const int k_in0 = (quarter & 1) * 16;
    u16 hib[16], lob[16];
    #pragma unroll
    for (int j = 0; j < 16; ++j) {
        float v = ws_[quarter * 16 + j][h] * scale;
        u16 hi = f2bf_trunc(v);
        hib[j] = hi;
        lob[j] = f2bf_trunc(v - bf2f(hi));
    }
    u16* dst = wtp + (size_t)n * 2048 + ks * 64;
    *(uint4*)(dst + k_in0)          = *(const uint4*)&hib[0];
    *(uint4*)(dst + k_in0 + 8)      = *(const uint4*)&hib[8];
    *(uint4*)(dst + 32 + k_in0)     = *(const uint4*)&lob[0];
    *(uint4*)(dst + 32 + k_in0 + 8) = *(const uint4*)&lob[8];
}

// ---------------- Projection GEMM: [8192 x 1024] @ [1024 x 192] ----------------
// 512 blocks x 16 rows (2 blocks/CU for latency hiding); 4 waves; wave = 16r x 48c.
#define NKS 32
#define XBUF(P) (smem + (P) * 2048)
#define BBUF(P) (smem + 4096 + (P) * 24576)

__global__ __launch_bounds__(256) void proj_gemm(
    const float* __restrict__ x, const u16* __restrict__ wtp,
    u16* __restrict__ qh8, u16* __restrict__ ql8,
    u16* __restrict__ kh,  u16* __restrict__ kl,
    u16* __restrict__ vt)
{
    __shared__ __align__(16) unsigned char smem[53248];  // x: 2*2KB, B: 2*24KB

    const int tid  = threadIdx.x;
    const int wave = tid >> 6, lane = tid & 63;
    const int lo4  = lane & 15, g = lane >> 4;
    const int row0 = blockIdx.x * 16;
    const int cbase = wave * 3;          // 3 col-tiles of 16 per wave

    f32x4 acc[3];
    #pragma unroll
    for (int c = 0; c < 3; ++c) acc[c] = (f32x4){0.f, 0.f, 0.f, 0.f};

    // x staging (waves 0-1): 16 rows x 32 fp32 = 128 chunks of 16B
    const int xr = tid >> 3, xc = tid & 7;
    const int xsw = (xc ^ (xr & 7)) << 2;
    const float* xsrc0 = x + (size_t)(row0 + (xr & 15)) * Dn + xsw;

    #define STAGE(P, KS)                                                     \
        {                                                                    \
            if (wave < 2) GLL16(xsrc0 + (KS) * 32, XBUF(P) + tid * 16);      \
            _Pragma("unroll")                                                \
            for (int i = 0; i < 6; ++i) {                                    \
                const int c = i * 256 + tid;                                 \
                const int n_ = c >> 3, p_ = c & 7;                           \
                const int l_ = p_ ^ (n_ & 7);                                \
                const u16* src = wtp + (size_t)n_ * 2048 + (KS) * 64         \
                                 + ((l_ & 3) << 3) + ((l_ >> 2) << 5);       \
                GLL16(src, BBUF(P) + c * 16);                                \
            }                                                                \
        }

    STAGE(0, 0)
    __syncthreads();
    int pb = 0;
    for (int ks = 0; ks < NKS; ++ks) {
        if (ks + 1 < NKS) STAGE(pb ^ 1, ks + 1)

        // A fragments: row = lo4, chunks 2g / 2g+1 (content-swizzled)
        bf16x8 ah, al;
        {
            const unsigned char* xb = XBUF(pb) + lo4 * 128;
            f32x4 f0 = *(const f32x4*)(xb + (((2 * g + 0) ^ (lo4 & 7)) << 4));
            f32x4 f1 = *(const f32x4*)(xb + (((2 * g + 1) ^ (lo4 & 7)) << 4));
            #pragma unroll
            for (int j = 0; j < 4; ++j) {
                u16 h0 = f2bf_trunc(f0[j]);
                ah[j] = (short)h0;
                al[j] = (short)f2bf_trunc(f0[j] - bf2f(h0));
                u16 h1 = f2bf_trunc(f1[j]);
                ah[4 + j] = (short)h1;
                al[4 + j] = (short)f2bf_trunc(f1[j] - bf2f(h1));
            }
        }
        // B fragments + MFMA (emu: xh*wh + xl*wh + xh*wl)
        #pragma unroll
        for (int ct = 0; ct < 3; ++ct) {
            const int n = (cbase + ct) * 16 + lo4;
            const unsigned char* bb = BBUF(pb) + n * 128;
            bf16x8 bh = *(const bf16x8*)(bb + (((g)     ^ (n & 7)) << 4));
            bf16x8 bl = *(const bf16x8*)(bb + (((4 + g) ^ (n & 7)) << 4));
            acc[ct] = __builtin_amdgcn_mfma_f32_16x16x32_bf16(ah, bh, acc[ct], 0, 0, 0);
            acc[ct] = __builtin_amdgcn_mfma_f32_16x16x32_bf16(al, bh, acc[ct], 0, 0, 0);
            acc[ct] = __builtin_amdgcn_mfma_f32_16x16x32_bf16(ah, bl, acc[ct], 0, 0, 0);
        }
        __syncthreads();
        pb ^= 1;
    }

    // epilogue: C layout col=lane&15, row=g*4+reg
    const int grow = row0 + g * 4;
    #pragma unroll
    for (int ct = 0; ct < 3; ++ct) {
        const int n = (cbase + ct) * 16 + lo4;
        if (n < 64) {
            #pragma unroll
            for (int reg = 0; reg < 4; ++reg) {
                float v = acc[ct][reg];
                u16 hi = f2bf_trunc(v);
                kh[(size_t)(grow + reg) * HSn + n] = hi;
                kl[(size_t)(grow + reg) * HSn + n] = f2bf_trunc(v - bf2f(hi));
            }
        } else if (n < 128) {
            #pragma unroll
            for (int reg = 0; reg < 4; ++reg) {
                float v = acc[ct][reg];   // already *8 (folded into Wq)
                u16 hi = f2bf_trunc(v);
                qh8[(size_t)(grow + reg) * HSn + (n - 64)] = hi;
                ql8[(size_t)(grow + reg) * HSn + (n - 64)] = f2bf_trunc(v - bf2f(hi));
            }
        } else {
            s16x4 pack;
            #pragma unroll
            for (int reg = 0; reg < 4; ++reg)
                pack[reg] = (short)f2bf_rne(acc[ct][reg]);
            const int b = grow >> 11, tl = grow & 2047;
            *(s16x4*)(vt + ((size_t)b * HSn + (n - 128)) * Tn + tl) = pack;
        }
    }
}

// ---------------- MFMA flash attention v2: reg-staged K/V, no spill ----------------
struct KVset {
    bf16x8 kh0[2], kh1[2], kl0[2], kl1[2], vf[4];
};

__global__ __launch_bounds__(256, 2) void attn_kernel(
    const u16* __restrict__ qh8, const u16* __restrict__ ql8,
    const u16* __restrict__ kh, const u16* __restrict__ kl,
    const u16* __restrict__ vt, float* __restrict__ out)
{
    __shared__ __align__(16) unsigned char pbuf[4096];    // P: 4 waves x 1KB
    __shared__ __align__(16) float om_s[4][16][64];       // merge O
    __shared__ float ml_s[4][16][2];                      // merge m,l

    const int tid  = threadIdx.x;
    const int wave = tid >> 6, lane = tid & 63;
    const int lo4  = lane & 15, g = lane >> 4;

    const int sblk = blockIdx.x >> 8, c = blockIdx.x & 255;
    const int tb = sblk ? 127 - (c >> 1) : (c >> 1);
    const int b  = 2 * sblk + (c & 1);
    const int t0 = tb * 16;

    const u16* qhp = qh8 + ((size_t)b * Tn + t0) * HSn;
    const u16* qlp = ql8 + ((size_t)b * Tn + t0) * HSn;
    const u16* khp = kh + (size_t)b * Tn * HSn;
    const u16* klp = kl + (size_t)b * Tn * HSn;
    const u16* vtp = vt + (size_t)b * HSn * Tn;

    bf16x8 qfh[2], qfl[2];
    #pragma unroll
    for (int ch = 0; ch < 2; ++ch) {
        qfh[ch] = *(const bf16x8*)(qhp + lo4 * HSn + ch * 32 + g * 8);
        qfl[ch] = *(const bf16x8*)(qlp + lo4 * HSn + ch * 32 + g * 8);
    }

    f32x4 O[4];
    #pragma unroll
    for (int n = 0; n < 4; ++n) O[n] = (f32x4){0.f, 0.f, 0.f, 0.f};
    float mrow[4], lrow[4];
    #pragma unroll
    for (int r = 0; r < 4; ++r) { mrow[r] = -1e30f; lrow[r] = 0.f; }

    const int nt = (t0 + 15) / 32 + 1;
    unsigned char* myPB = pbuf + wave * 1024;

    #define LOADSET(S, J)                                                     \
        {                                                                     \
            const int s0_ = (J) * 32;                                         \
            _Pragma("unroll")                                                 \
            for (int sb = 0; sb < 2; ++sb) {                                  \
                const u16* kr = khp + (size_t)(s0_ + sb * 16 + lo4) * HSn;    \
                const u16* lr = klp + (size_t)(s0_ + sb * 16 + lo4) * HSn;    \
                S.kh0[sb] = *(const bf16x8*)(kr + g * 8);                     \
                S.kh1[sb] = *(const bf16x8*)(kr + 32 + g * 8);                \
                S.kl0[sb] = *(const bf16x8*)(lr + g * 8);                     \
                S.kl1[sb] = *(const bf16x8*)(lr + 32 + g * 8);                \
            }                                                                 \
            _Pragma("unroll")                                                 \
            for (int n = 0; n < 4; ++n)                                       \
                S.vf[n] = *(const bf16x8*)(vtp + (size_t)(n * 16 + lo4) * Tn  \
                                           + s0_ + g * 8);                    \
        }

    #define COMPUTE(S, J)                                                     \
        {                                                                     \
            const int s0 = (J) * 32;                                          \
            f32x4 accS[2];                                                    \
            __builtin_amdgcn_s_setprio(1);                                    \
            _Pragma("unroll")                                                 \
            for (int sb = 0; sb < 2; ++sb) {                                  \
                f32x4 a = (f32x4){0.f, 0.f, 0.f, 0.f};                        \
                a = __builtin_amdgcn_mfma_f32_16x16x32_bf16(qfh[0], S.kh0[sb], a, 0, 0, 0); \
                a = __builtin_amdgcn_mfma_f32_16x16x32_bf16(qfh[1], S.kh1[sb], a, 0, 0, 0); \
                a = __builtin_amdgcn_mfma_f32_16x16x32_bf16(qfl[0], S.kh0[sb], a, 0, 0, 0); \
                a = __builtin_amdgcn_mfma_f32_16x16x32_bf16(qfl[1], S.kh1[sb], a, 0, 0, 0); \
                a = __builtin_amdgcn_mfma_f32_16x16x32_bf16(qfh[0], S.kl0[sb], a, 0, 0, 0); \
                a = __builtin_amdgcn_mfma_f32_16x16x32_bf16(qfh[1], S.kl1[sb], a, 0, 0, 0); \
                accS[sb] = a;                                                 \
            }                                                                 \
            __builtin_amdgcn_s_setprio(0);                                    \
            _Pragma("unroll")                                                 \
            for (int reg = 0; reg < 4; ++reg) {                               \
                const int tg  = t0 + g * 4 + reg;                             \
                const int sg0 = s0 + lo4;                                     \
                const int sg1 = s0 + 16 + lo4;                                \
                float v0 = (sg0 <= tg) ? accS[0][reg] : -1e30f;               \
                float v1 = (sg1 <= tg) ? accS[1][reg] : -1e30f;               \
                float mt = fmaxf(v0, v1);                                     \
                mt = fmaxf(mt, __shfl_xor(mt, 1));                            \
                mt = fmaxf(mt, __shfl_xor(mt, 2));                            \
                mt = fmaxf(mt, __shfl_xor(mt, 4));                            \
                mt = fmaxf(mt, __shfl_xor(mt, 8));                            \
                float mn = fmaxf(mrow[reg], mt);                              \
                float p0 = (sg0 <= tg) ? __expf(v0 - mn) : 0.f;               \
                float p1 = (sg1 <= tg) ? __expf(v1 - mn) : 0.f;               \
                float ps = p0 + p1;                                           \
                ps += __shfl_xor(ps, 1);                                      \
                ps += __shfl_xor(ps, 2);                                      \
                ps += __shfl_xor(ps, 4);                                      \
                ps += __shfl_xor(ps, 8);                                      \
                float alpha = __expf(mrow[reg] - mn);                         \
                lrow[reg] = lrow[reg] * alpha + ps;                           \
                mrow[reg] = mn;                                               \
                _Pragma("unroll")                                             \
                for (int n = 0; n < 4; ++n) O[n][reg] *= alpha;               \
                const int irow = g * 4 + reg;                                 \
                *(u16*)(myPB + ((irow * 64 + lo4 * 2) ^ (reg << 4)))      = f2bf_rne(p0); \
                *(u16*)(myPB + ((irow * 64 + 32 + lo4 * 2) ^ (reg << 4))) = f2bf_rne(p1); \
            }                                                                 \
            bf16x8 pf = *(const bf16x8*)(myPB + ((lo4 * 64 + 16 * g) ^ ((lo4 & 3) << 4))); \
            __builtin_amdgcn_s_setprio(1);                                    \
            _Pragma("unroll")                                                 \
            for (int n = 0; n < 4; ++n)                                       \
                O[n] = __builtin_amdgcn_mfma_f32_16x16x32_bf16(pf, S.vf[n], O[n], 0, 0, 0); \
            __builtin_amdgcn_s_setprio(0);                                    \
        }

    KVset A, B;
    int j = wave;
    if (j < nt) LOADSET(A, j)
    while (j < nt) {
        if (j + 4 < nt) LOADSET(B, j + 4)
        COMPUTE(A, j)
        if (j + 4 < nt) {
            if (j + 8 < nt) LOADSET(A, j + 8)
            COMPUTE(B, j + 4)
        }
        j += 8;
    }

    // per-wave partials -> LDS
    #pragma unroll
    for (int n = 0; n < 4; ++n)
        #pragma unroll
        for (int reg = 0; reg < 4; ++reg)
            om_s[wave][g * 4 + reg][n * 16 + lo4] = O[n][reg];
    if (lo4 == 0) {
        #pragma unroll
        for (int reg = 0; reg < 4; ++reg) {
            ml_s[wave][g * 4 + reg][0] = mrow[reg];
            ml_s[wave][g * 4 + reg][1] = lrow[reg];
        }
    }
    __syncthreads();

    // merge 4 partials: thread -> (row r, 4 h's)
    const int r  = tid >> 4;
    const int h4 = (tid & 15) * 4;
    float mw[4], lw[4], mstar = -1e30f;
    #pragma unroll
    for (int w = 0; w < 4; ++w) {
        mw[w] = ml_s[w][r][0];
        lw[w] = ml_s[w][r][1];
        mstar = fmaxf(mstar, mw[w]);
    }
    float lstar = 0.f, ew[4];
    #pragma unroll
    for (int w = 0; w < 4; ++w) { ew[w] = __expf(mw[w] - mstar); lstar += lw[w] * ew[w]; }
    float4 a4 = {0.f, 0.f, 0.f, 0.f};
    #pragma unroll
    for (int w = 0; w < 4; ++w) {
        float4 t4 = *(const float4*)&om_s[w][r][h4];
        a4.x += t4.x * ew[w]; a4.y += t4.y * ew[w];
        a4.z += t4.z * ew[w]; a4.w += t4.w * ew[w];
    }
    const float inv = 1.f / lstar;
    a4.x *= inv; a4.y *= inv; a4.z *= inv; a4.w *= inv;
    *(float4*)(out + ((size_t)b * Tn + t0 + r) * HSn + h4) = a4;
}

extern "C" void kernel_launch(void* const* d_in, const int* in_sizes, int n_in,
                              void* d_out, int out_size, void* d_ws, size_t ws_size,
                              hipStream_t stream) {
    const float* x  = (const float*)d_in[0];
    const float* Wk = (const float*)d_in[1];
    const float* Wq = (const float*)d_in[2];
    const float* Wv = (const float*)d_in[3];
    float* out = (float*)d_out;

    const size_t per = (size_t)Bn * Tn * HSn;   // 524288
    u16* qh8 = (u16*)d_ws;
    u16* ql8 = qh8 + per;
    u16* khw = ql8 + per;
    u16* klw = khw + per;
    u16* vtw = klw + per;
    u16* wtp = vtw + per;                       // 192*2048 u16 = 768 KB

    hipLaunchKernelGGL(wprep_kernel, dim3(16, 3), dim3(256), 0, stream,
                       Wk, Wq, Wv, wtp);
    hipLaunchKernelGGL(proj_gemm, dim3(512), dim3(256), 0, stream,
                       x, wtp, qh8, ql8, khw, klw, vtw);
    hipLaunchKernelGGL(attn_kernel, dim3(512), dim3(256), 0, stream,
                       qh8, ql8, khw, klw, vtw, out);
}

// Round 7
// 55.018 us; speedup vs baseline: 5.2433x; 1.0847x over previous
//
#include <hip/hip_runtime.h>

#define Bn 4
#define Tn 2048
#define Dn 1024
#define HSn 64

typedef __attribute__((ext_vector_type(8))) short bf16x8;
typedef __attribute__((ext_vector_type(4))) float f32x4;
typedef __attribute__((ext_vector_type(4))) short s16x4;
typedef unsigned short u16;
typedef unsigned int u32;

__device__ __forceinline__ u16 f2bf_rne(float x) {
    u32 u = __float_as_uint(x);
    return (u16)((u + 0x7FFFu + ((u >> 16) & 1u)) >> 16);
}
__device__ __forceinline__ u16 f2bf_trunc(float x) {
    return (u16)(__float_as_uint(x) >> 16);
}
__device__ __forceinline__ float bf2f(u16 h) {
    return __uint_as_float(((u32)h) << 16);
}

#define GLL16(g, l)                                                        \
    __builtin_amdgcn_global_load_lds(                                      \
        (const __attribute__((address_space(1))) void*)(g),                \
        (__attribute__((address_space(3))) void*)(l), 16, 0, 0)

// ---------------- Prep: W^T hi/lo bf16, packed per k-step ----------------
// wtp[n][ks][0:32]=hi bf16, [32:64]=lo bf16  (n: 0-63 Wk, 64-127 Wq*8, 128-191 Wv)
__global__ __launch_bounds__(256) void wprep_kernel(
    const float* __restrict__ Wk, const float* __restrict__ Wq,
    const float* __restrict__ Wv, u16* __restrict__ wtp)
{
    __shared__ float ws_[64][65];
    const int kb = blockIdx.x;        // k-tile of 64
    const int w  = blockIdx.y;        // 0=Wk,1=Wq,2=Wv
    const float* __restrict__ W = (w == 0) ? Wk : (w == 1) ? Wq : Wv;
    const float scale = (w == 1) ? 8.0f : 1.0f;   // fold *sqrt(HS) into Wq
    const int t = threadIdx.x;

    {
        const int kl = t >> 2, hq = t & 3;
        #pragma unroll
        for (int i = 0; i < 4; ++i) {
            float4 f = *(const float4*)(W + (size_t)(kb * 64 + kl) * 64 + hq * 16 + i * 4);
            ws_[kl][hq * 16 + i * 4 + 0] = f.x; ws_[kl][hq * 16 + i * 4 + 1] = f.y;
            ws_[kl][hq * 16 + i * 4 + 2] = f.z; ws_[kl][hq * 16 + i * 4 + 3] = f.w;
        }
    }
    __syncthreads();

    const int h = t & 63, quarter = t >> 6;
    const int n = w * 64 + h;
    const int ks = kb * 2 + (quarter >> 1);
    const int k_in0 = (quarter & 1) * 16;
    u16 hib[16], lob[16];
    #pragma unroll
    for (int j = 0; j < 16; ++j) {
        float v = ws_[quarter * 16 + j][h] * scale;
        u16 hi = f2bf_trunc(v);
        hib[j] = hi;
        lob[j] = f2bf_trunc(v - bf2f(hi));
    }
    u16* dst = wtp + (size_t)n * 2048 + ks * 64;
    *(uint4*)(dst + k_in0)          = *(const uint4*)&hib[0];
    *(uint4*)(dst + k_in0 + 8)      = *(const uint4*)&hib[8];
    *(uint4*)(dst + 32 + k_in0)     = *(const uint4*)&lob[0];
    *(uint4*)(dst + 32 + k_in0 + 8) = *(const uint4*)&lob[8];
}

// ---------------- Projection GEMM: [8192 x 1024] @ [1024 x 192] ----------------
// 256 blocks x 512 threads x 32 rows; 8 waves = 2 row-tiles x 4 col-groups(48c).
// 3-stage LDS pipeline, counted vmcnt + raw barrier (no full drains in loop).
#define NKS 32
#define XB(P) (smem + (P) * 4096)            // 32 rows x 128 B
#define BB(P) (smem + 12288 + (P) * 24576)   // 192 cols x 128 B

__global__ __launch_bounds__(512) void proj_gemm(
    const float* __restrict__ x, const u16* __restrict__ wtp,
    u16* __restrict__ qh8, u16* __restrict__ ql8,
    u16* __restrict__ kh,  u16* __restrict__ kl,
    u16* __restrict__ vt)
{
    __shared__ __align__(16) unsigned char smem[86016];  // 3 x (4KB x + 24KB W)

    const int tid  = threadIdx.x;
    const int wave = tid >> 6, lane = tid & 63;
    const int lo4  = lane & 15, g = lane >> 4;
    const int row0 = blockIdx.x * 32;
    const int rt   = wave >> 2;          // row-tile 0/1
    const int cbase = (wave & 3) * 3;    // 3 col-tiles of 16 per wave
    const int rl = rt * 16 + lo4;        // local row for A-frag

    f32x4 acc[3];
    #pragma unroll
    for (int c = 0; c < 3; ++c) acc[c] = (f32x4){0.f, 0.f, 0.f, 0.f};

    // x staging (threads 0-255): 32 rows x 32 fp32 = 256 chunks of 16B
    const int xr = (tid >> 3) & 31, xc = tid & 7;
    const int xsw = (xc ^ (xr & 7)) << 2;
    const float* xsrc0 = x + (size_t)(row0 + xr) * Dn + xsw;

    #define STAGE(P, KS)                                                     \
        {                                                                    \
            if (tid < 256) GLL16(xsrc0 + (KS) * 32, XB(P) + tid * 16);       \
            _Pragma("unroll")                                                \
            for (int i = 0; i < 3; ++i) {                                    \
                const int c = i * 512 + tid;                                 \
                const int n_ = c >> 3, p_ = c & 7;                           \
                const int l_ = p_ ^ (n_ & 7);                                \
                const u16* src = wtp + (size_t)n_ * 2048 + (KS) * 64         \
                                 + ((l_ & 3) << 3) + ((l_ >> 2) << 5);       \
                GLL16(src, BB(P) + c * 16);                                  \
            }                                                                \
        }

    #define COMPUTE(P, KS)                                                   \
        {                                                                    \
            bf16x8 ah, al;                                                   \
            {                                                                \
                const unsigned char* xb = XB(P) + rl * 128;                  \
                f32x4 f0 = *(const f32x4*)(xb + (((2 * g + 0) ^ (rl & 7)) << 4)); \
                f32x4 f1 = *(const f32x4*)(xb + (((2 * g + 1) ^ (rl & 7)) << 4)); \
                _Pragma("unroll")                                            \
                for (int jj = 0; jj < 4; ++jj) {                             \
                    u16 h0 = f2bf_trunc(f0[jj]);                             \
                    ah[jj] = (short)h0;                                      \
                    al[jj] = (short)f2bf_trunc(f0[jj] - bf2f(h0));           \
                    u16 h1 = f2bf_trunc(f1[jj]);                             \
                    ah[4 + jj] = (short)h1;                                  \
                    al[4 + jj] = (short)f2bf_trunc(f1[jj] - bf2f(h1));       \
                }                                                            \
            }                                                                \
            _Pragma("unroll")                                                \
            for (int ct = 0; ct < 3; ++ct) {                                 \
                const int n = (cbase + ct) * 16 + lo4;                       \
                const unsigned char* bb = BB(P) + n * 128;                   \
                bf16x8 bh = *(const bf16x8*)(bb + (((g)     ^ (n & 7)) << 4)); \
                bf16x8 bl = *(const bf16x8*)(bb + (((4 + g) ^ (n & 7)) << 4)); \
                acc[ct] = __builtin_amdgcn_mfma_f32_16x16x32_bf16(ah, bh, acc[ct], 0, 0, 0); \
                acc[ct] = __builtin_amdgcn_mfma_f32_16x16x32_bf16(al, bh, acc[ct], 0, 0, 0); \
                acc[ct] = __builtin_amdgcn_mfma_f32_16x16x32_bf16(ah, bl, acc[ct], 0, 0, 0); \
            }                                                                \
        }

    STAGE(0, 0)
    STAGE(1, 1)
    int pb = 0;
    for (int ks = 0; ks < NKS; ++ks) {
        // wait for stage(ks) to have landed (leave stage(ks+1) in flight)
        if (ks == NKS - 1) {
            asm volatile("s_waitcnt vmcnt(0)" ::: "memory");
        } else if (wave < 4) {
            asm volatile("s_waitcnt vmcnt(4)" ::: "memory");   // 1 x-load + 3 W-loads in flight
        } else {
            asm volatile("s_waitcnt vmcnt(3)" ::: "memory");   // 3 W-loads in flight
        }
        __builtin_amdgcn_s_barrier();
        asm volatile("" ::: "memory");

        int ps = pb + 2; if (ps >= 3) ps -= 3;
        if (ks + 2 < NKS) STAGE(ps, ks + 2)
        COMPUTE(pb, ks)
        pb = (pb == 2) ? 0 : pb + 1;
    }

    // epilogue: C layout col=lane&15, row=g*4+reg
    const int grow = row0 + rt * 16 + g * 4;
    #pragma unroll
    for (int ct = 0; ct < 3; ++ct) {
        const int n = (cbase + ct) * 16 + lo4;
        if (n < 64) {
            #pragma unroll
            for (int reg = 0; reg < 4; ++reg) {
                float v = acc[ct][reg];
                u16 hi = f2bf_trunc(v);
                kh[(size_t)(grow + reg) * HSn + n] = hi;
                kl[(size_t)(grow + reg) * HSn + n] = f2bf_trunc(v - bf2f(hi));
            }
        } else if (n < 128) {
            #pragma unroll
            for (int reg = 0; reg < 4; ++reg) {
                float v = acc[ct][reg];   // already *8 (folded into Wq)
                u16 hi = f2bf_trunc(v);
                qh8[(size_t)(grow + reg) * HSn + (n - 64)] = hi;
                ql8[(size_t)(grow + reg) * HSn + (n - 64)] = f2bf_trunc(v - bf2f(hi));
            }
        } else {
            s16x4 pack;
            #pragma unroll
            for (int reg = 0; reg < 4; ++reg)
                pack[reg] = (short)f2bf_rne(acc[ct][reg]);
            const int b = grow >> 11, tl = grow & 2047;
            *(s16x4*)(vt + ((size_t)b * HSn + (n - 128)) * Tn + tl) = pack;
        }
    }
}

// ---------------- MFMA flash attention v2: reg-staged K/V, no spill ----------------
struct KVset {
    bf16x8 kh0[2], kh1[2], kl0[2], kl1[2], vf[4];
};

__global__ __launch_bounds__(256, 2) void attn_kernel(
    const u16* __restrict__ qh8, const u16* __restrict__ ql8,
    const u16* __restrict__ kh, const u16* __restrict__ kl,
    const u16* __restrict__ vt, float* __restrict__ out)
{
    __shared__ __align__(16) unsigned char pbuf[4096];    // P: 4 waves x 1KB
    __shared__ __align__(16) float om_s[4][16][64];       // merge O
    __shared__ float ml_s[4][16][2];                      // merge m,l

    const int tid  = threadIdx.x;
    const int wave = tid >> 6, lane = tid & 63;
    const int lo4  = lane & 15, g = lane >> 4;

    const int sblk = blockIdx.x >> 8, c = blockIdx.x & 255;
    const int tb = sblk ? 127 - (c >> 1) : (c >> 1);
    const int b  = 2 * sblk + (c & 1);
    const int t0 = tb * 16;

    const u16* qhp = qh8 + ((size_t)b * Tn + t0) * HSn;
    const u16* qlp = ql8 + ((size_t)b * Tn + t0) * HSn;
    const u16* khp = kh + (size_t)b * Tn * HSn;
    const u16* klp = kl + (size_t)b * Tn * HSn;
    const u16* vtp = vt + (size_t)b * HSn * Tn;

    bf16x8 qfh[2], qfl[2];
    #pragma unroll
    for (int ch = 0; ch < 2; ++ch) {
        qfh[ch] = *(const bf16x8*)(qhp + lo4 * HSn + ch * 32 + g * 8);
        qfl[ch] = *(const bf16x8*)(qlp + lo4 * HSn + ch * 32 + g * 8);
    }

    f32x4 O[4];
    #pragma unroll
    for (int n = 0; n < 4; ++n) O[n] = (f32x4){0.f, 0.f, 0.f, 0.f};
    float mrow[4], lrow[4];
    #pragma unroll
    for (int r = 0; r < 4; ++r) { mrow[r] = -1e30f; lrow[r] = 0.f; }

    const int nt = (t0 + 15) / 32 + 1;
    unsigned char* myPB = pbuf + wave * 1024;

    #define LOADSET(S, J)                                                     \
        {                                                                     \
            const int s0_ = (J) * 32;                                         \
            _Pragma("unroll")                                                 \
            for (int sb = 0; sb < 2; ++sb) {                                  \
                const u16* kr = khp + (size_t)(s0_ + sb * 16 + lo4) * HSn;    \
                const u16* lr = klp + (size_t)(s0_ + sb * 16 + lo4) * HSn;    \
                S.kh0[sb] = *(const bf16x8*)(kr + g * 8);                     \
                S.kh1[sb] = *(const bf16x8*)(kr + 32 + g * 8);                \
                S.kl0[sb] = *(const bf16x8*)(lr + g * 8);                     \
                S.kl1[sb] = *(const bf16x8*)(lr + 32 + g * 8);                \
            }                                                                 \
            _Pragma("unroll")                                                 \
            for (int n = 0; n < 4; ++n)                                       \
                S.vf[n] = *(const bf16x8*)(vtp + (size_t)(n * 16 + lo4) * Tn  \
                                           + s0_ + g * 8);                    \
        }

    #define COMPUTE_ATT(S, J)                                                 \
        {                                                                     \
            const int s0 = (J) * 32;                                          \
            f32x4 accS[2];                                                    \
            __builtin_amdgcn_s_setprio(1);                                    \
            _Pragma("unroll")                                                 \
            for (int sb = 0; sb < 2; ++sb) {                                  \
                f32x4 a = (f32x4){0.f, 0.f, 0.f, 0.f};                        \
                a = __builtin_amdgcn_mfma_f32_16x16x32_bf16(qfh[0], S.kh0[sb], a, 0, 0, 0); \
                a = __builtin_amdgcn_mfma_f32_16x16x32_bf16(qfh[1], S.kh1[sb], a, 0, 0, 0); \
                a = __builtin_amdgcn_mfma_f32_16x16x32_bf16(qfl[0], S.kh0[sb], a, 0, 0, 0); \
                a = __builtin_amdgcn_mfma_f32_16x16x32_bf16(qfl[1], S.kh1[sb], a, 0, 0, 0); \
                a = __builtin_amdgcn_mfma_f32_16x16x32_bf16(qfh[0], S.kl0[sb], a, 0, 0, 0); \
                a = __builtin_amdgcn_mfma_f32_16x16x32_bf16(qfh[1], S.kl1[sb], a, 0, 0, 0); \
                accS[sb] = a;                                                 \
            }                                                                 \
            __builtin_amdgcn_s_setprio(0);                                    \
            _Pragma("unroll")                                                 \
            for (int reg = 0; reg < 4; ++reg) {                               \
                const int tg  = t0 + g * 4 + reg;                             \
                const int sg0 = s0 + lo4;                                     \
                const int sg1 = s0 + 16 + lo4;                                \
                float v0 = (sg0 <= tg) ? accS[0][reg] : -1e30f;               \
                float v1 = (sg1 <= tg) ? accS[1][reg] : -1e30f;               \
                float mt = fmaxf(v0, v1);                                     \
                mt = fmaxf(mt, __shfl_xor(mt, 1));                            \
                mt = fmaxf(mt, __shfl_xor(mt, 2));                            \
                mt = fmaxf(mt, __shfl_xor(mt, 4));                            \
                mt = fmaxf(mt, __shfl_xor(mt, 8));                            \
                float mn = fmaxf(mrow[reg], mt);                              \
                float p0 = (sg0 <= tg) ? __expf(v0 - mn) : 0.f;               \
                float p1 = (sg1 <= tg) ? __expf(v1 - mn) : 0.f;               \
                float ps = p0 + p1;                                           \
                ps += __shfl_xor(ps, 1);                                      \
                ps += __shfl_xor(ps, 2);                                      \
                ps += __shfl_xor(ps, 4);                                      \
                ps += __shfl_xor(ps, 8);                                      \
                float alpha = __expf(mrow[reg] - mn);                         \
                lrow[reg] = lrow[reg] * alpha + ps;                           \
                mrow[reg] = mn;                                               \
                _Pragma("unroll")                                             \
                for (int n = 0; n < 4; ++n) O[n][reg] *= alpha;               \
                const int irow = g * 4 + reg;                                 \
                *(u16*)(myPB + ((irow * 64 + lo4 * 2) ^ (reg << 4)))      = f2bf_rne(p0); \
                *(u16*)(myPB + ((irow * 64 + 32 + lo4 * 2) ^ (reg << 4))) = f2bf_rne(p1); \
            }                                                                 \
            bf16x8 pf = *(const bf16x8*)(myPB + ((lo4 * 64 + 16 * g) ^ ((lo4 & 3) << 4))); \
            __builtin_amdgcn_s_setprio(1);                                    \
            _Pragma("unroll")                                                 \
            for (int n = 0; n < 4; ++n)                                       \
                O[n] = __builtin_amdgcn_mfma_f32_16x16x32_bf16(pf, S.vf[n], O[n], 0, 0, 0); \
            __builtin_amdgcn_s_setprio(0);                                    \
        }

    KVset A, B;
    int j = wave;
    if (j < nt) LOADSET(A, j)
    while (j < nt) {
        if (j + 4 < nt) LOADSET(B, j + 4)
        COMPUTE_ATT(A, j)
        if (j + 4 < nt) {
            if (j + 8 < nt) LOADSET(A, j + 8)
            COMPUTE_ATT(B, j + 4)
        }
        j += 8;
    }

    // per-wave partials -> LDS
    #pragma unroll
    for (int n = 0; n < 4; ++n)
        #pragma unroll
        for (int reg = 0; reg < 4; ++reg)
            om_s[wave][g * 4 + reg][n * 16 + lo4] = O[n][reg];
    if (lo4 == 0) {
        #pragma unroll
        for (int reg = 0; reg < 4; ++reg) {
            ml_s[wave][g * 4 + reg][0] = mrow[reg];
            ml_s[wave][g * 4 + reg][1] = lrow[reg];
        }
    }
    __syncthreads();

    // merge 4 partials: thread -> (row r, 4 h's)
    const int r  = tid >> 4;
    const int h4 = (tid & 15) * 4;
    float mw[4], lw[4], mstar = -1e30f;
    #pragma unroll
    for (int w = 0; w < 4; ++w) {
        mw[w] = ml_s[w][r][0];
        lw[w] = ml_s[w][r][1];
        mstar = fmaxf(mstar, mw[w]);
    }
    float lstar = 0.f, ew[4];
    #pragma unroll
    for (int w = 0; w < 4; ++w) { ew[w] = __expf(mw[w] - mstar); lstar += lw[w] * ew[w]; }
    float4 a4 = {0.f, 0.f, 0.f, 0.f};
    #pragma unroll
    for (int w = 0; w < 4; ++w) {
        float4 t4 = *(const float4*)&om_s[w][r][h4];
        a4.x += t4.x * ew[w]; a4.y += t4.y * ew[w];
        a4.z += t4.z * ew[w]; a4.w += t4.w * ew[w];
    }
    const float inv = 1.f / lstar;
    a4.x *= inv; a4.y *= inv; a4.z *= inv; a4.w *= inv;
    *(float4*)(out + ((size_t)b * Tn + t0 + r) * HSn + h4) = a4;
}

extern "C" void kernel_launch(void* const* d_in, const int* in_sizes, int n_in,
                              void* d_out, int out_size, void* d_ws, size_t ws_size,
                              hipStream_t stream) {
    const float* x  = (const float*)d_in[0];
    const float* Wk = (const float*)d_in[1];
    const float* Wq = (const float*)d_in[2];
    const float* Wv = (const float*)d_in[3];
    float* out = (float*)d_out;

    const size_t per = (size_t)Bn * Tn * HSn;   // 524288
    u16* qh8 = (u16*)d_ws;
    u16* ql8 = qh8 + per;
    u16* khw = ql8 + per;
    u16* klw = khw + per;
    u16* vtw = klw + per;
    u16* wtp = vtw + per;                       // 192*2048 u16 = 768 KB

    hipLaunchKernelGGL(wprep_kernel, dim3(16, 3), dim3(256), 0, stream,
                       Wk, Wq, Wv, wtp);
    hipLaunchKernelGGL(proj_gemm, dim3(256), dim3(512), 0, stream,
                       x, wtp, qh8, ql8, khw, klw, vtw);
    hipLaunchKernelGGL(attn_kernel, dim3(512), dim3(256), 0, stream,
                       qh8, ql8, khw, klw, vtw, out);
}

// Round 8
// 49.478 us; speedup vs baseline: 5.8304x; 1.1120x over previous
//
#include <hip/hip_runtime.h>

#define Bn 4
#define Tn 2048
#define Dn 1024
#define HSn 64

typedef __attribute__((ext_vector_type(8))) short bf16x8;
typedef __attribute__((ext_vector_type(4))) float f32x4;
typedef __attribute__((ext_vector_type(4))) short s16x4;
typedef unsigned short u16;
typedef unsigned int u32;

__device__ __forceinline__ u16 f2bf_rne(float x) {
    u32 u = __float_as_uint(x);
    return (u16)((u + 0x7FFFu + ((u >> 16) & 1u)) >> 16);
}
__device__ __forceinline__ u16 f2bf_trunc(float x) {
    return (u16)(__float_as_uint(x) >> 16);
}
__device__ __forceinline__ float bf2f(u16 h) {
    return __uint_as_float(((u32)h) << 16);
}

#define GLL16(g, l)                                                        \
    __builtin_amdgcn_global_load_lds(                                      \
        (const __attribute__((address_space(1))) void*)(g),                \
        (__attribute__((address_space(3))) void*)(l), 16, 0, 0)

// ---------------- Prep: W^T hi/lo bf16, packed per k-step ----------------
__global__ __launch_bounds__(256) void wprep_kernel(
    const float* __restrict__ Wk, const float* __restrict__ Wq,
    const float* __restrict__ Wv, u16* __restrict__ wtp)
{
    __shared__ float ws_[64][65];
    const int kb = blockIdx.x;
    const int w  = blockIdx.y;
    const float* __restrict__ W = (w == 0) ? Wk : (w == 1) ? Wq : Wv;
    const float scale = (w == 1) ? 8.0f : 1.0f;
    const int t = threadIdx.x;

    {
        const int kl = t >> 2, hq = t & 3;
        #pragma unroll
        for (int i = 0; i < 4; ++i) {
            float4 f = *(const float4*)(W + (size_t)(kb * 64 + kl) * 64 + hq * 16 + i * 4);
            ws_[kl][hq * 16 + i * 4 + 0] = f.x; ws_[kl][hq * 16 + i * 4 + 1] = f.y;
            ws_[kl][hq * 16 + i * 4 + 2] = f.z; ws_[kl][hq * 16 + i * 4 + 3] = f.w;
        }
    }
    __syncthreads();

    const int h = t & 63, quarter = t >> 6;
    const int n = w * 64 + h;
    const int ks = kb * 2 + (quarter >> 1);
    const int k_in0 = (quarter & 1) * 16;
    u16 hib[16], lob[16];
    #pragma unroll
    for (int j = 0; j < 16; ++j) {
        float v = ws_[quarter * 16 + j][h] * scale;
        u16 hi = f2bf_trunc(v);
        hib[j] = hi;
        lob[j] = f2bf_trunc(v - bf2f(hi));
    }
    u16* dst = wtp + (size_t)n * 2048 + ks * 64;
    *(uint4*)(dst + k_in0)          = *(const uint4*)&hib[0];
    *(uint4*)(dst + k_in0 + 8)      = *(const uint4*)&hib[8];
    *(uint4*)(dst + 32 + k_in0)     = *(const uint4*)&lob[0];
    *(uint4*)(dst + 32 + k_in0 + 8) = *(const uint4*)&lob[8];
}

// ---------------- Projection GEMM: [8192 x 1024] @ [1024 x 192] ----------------
// 256 blocks x 512 threads x 32 rows; 3-stage pipeline, counted vmcnt + raw barrier.
// Epilogue emits K/V in MFMA-fragment-tiled layouts for coalesced attn loads:
//   K: kt[b][s/16][ch(2)][g(4)][r(16)][e(8)]  (hi and lo arrays)
//   V: vt[b][s/32][n(4)][lo4(16)][g(4)][e(8)]
#define NKS 32
#define XB(P) (smem + (P) * 4096)
#define BB(P) (smem + 12288 + (P) * 24576)

__global__ __launch_bounds__(512) void proj_gemm(
    const float* __restrict__ x, const u16* __restrict__ wtp,
    u16* __restrict__ qh8, u16* __restrict__ ql8,
    u16* __restrict__ kth, u16* __restrict__ ktl,
    u16* __restrict__ vtt)
{
    __shared__ __align__(16) unsigned char smem[86016];

    const int tid  = threadIdx.x;
    const int wave = tid >> 6, lane = tid & 63;
    const int lo4  = lane & 15, g = lane >> 4;
    const int row0 = blockIdx.x * 32;
    const int rt   = wave >> 2;
    const int cbase = (wave & 3) * 3;
    const int rl = rt * 16 + lo4;

    f32x4 acc[3];
    #pragma unroll
    for (int c = 0; c < 3; ++c) acc[c] = (f32x4){0.f, 0.f, 0.f, 0.f};

    const int xr = (tid >> 3) & 31, xc = tid & 7;
    const int xsw = (xc ^ (xr & 7)) << 2;
    const float* xsrc0 = x + (size_t)(row0 + xr) * Dn + xsw;

    #define STAGE(P, KS)                                                     \
        {                                                                    \
            if (tid < 256) GLL16(xsrc0 + (KS) * 32, XB(P) + tid * 16);       \
            _Pragma("unroll")                                                \
            for (int i = 0; i < 3; ++i) {                                    \
                const int c = i * 512 + tid;                                 \
                const int n_ = c >> 3, p_ = c & 7;                           \
                const int l_ = p_ ^ (n_ & 7);                                \
                const u16* src = wtp + (size_t)n_ * 2048 + (KS) * 64         \
                                 + ((l_ & 3) << 3) + ((l_ >> 2) << 5);       \
                GLL16(src, BB(P) + c * 16);                                  \
            }                                                                \
        }

    #define COMPUTE(P, KS)                                                   \
        {                                                                    \
            bf16x8 ah, al;                                                   \
            {                                                                \
                const unsigned char* xb = XB(P) + rl * 128;                  \
                f32x4 f0 = *(const f32x4*)(xb + (((2 * g + 0) ^ (rl & 7)) << 4)); \
                f32x4 f1 = *(const f32x4*)(xb + (((2 * g + 1) ^ (rl & 7)) << 4)); \
                _Pragma("unroll")                                            \
                for (int jj = 0; jj < 4; ++jj) {                             \
                    u16 h0 = f2bf_trunc(f0[jj]);                             \
                    ah[jj] = (short)h0;                                      \
                    al[jj] = (short)f2bf_trunc(f0[jj] - bf2f(h0));           \
                    u16 h1 = f2bf_trunc(f1[jj]);                             \
                    ah[4 + jj] = (short)h1;                                  \
                    al[4 + jj] = (short)f2bf_trunc(f1[jj] - bf2f(h1));       \
                }                                                            \
            }                                                                \
            _Pragma("unroll")                                                \
            for (int ct = 0; ct < 3; ++ct) {                                 \
                const int n = (cbase + ct) * 16 + lo4;                       \
                const unsigned char* bb = BB(P) + n * 128;                   \
                bf16x8 bh = *(const bf16x8*)(bb + (((g)     ^ (n & 7)) << 4)); \
                bf16x8 bl = *(const bf16x8*)(bb + (((4 + g) ^ (n & 7)) << 4)); \
                acc[ct] = __builtin_amdgcn_mfma_f32_16x16x32_bf16(ah, bh, acc[ct], 0, 0, 0); \
                acc[ct] = __builtin_amdgcn_mfma_f32_16x16x32_bf16(al, bh, acc[ct], 0, 0, 0); \
                acc[ct] = __builtin_amdgcn_mfma_f32_16x16x32_bf16(ah, bl, acc[ct], 0, 0, 0); \
            }                                                                \
        }

    STAGE(0, 0)
    STAGE(1, 1)
    int pb = 0;
    for (int ks = 0; ks < NKS; ++ks) {
        if (ks == NKS - 1) {
            asm volatile("s_waitcnt vmcnt(0)" ::: "memory");
        } else if (wave < 4) {
            asm volatile("s_waitcnt vmcnt(4)" ::: "memory");
        } else {
            asm volatile("s_waitcnt vmcnt(3)" ::: "memory");
        }
        __builtin_amdgcn_s_barrier();
        asm volatile("" ::: "memory");

        int ps = pb + 2; if (ps >= 3) ps -= 3;
        if (ks + 2 < NKS) STAGE(ps, ks + 2)
        COMPUTE(pb, ks)
        pb = (pb == 2) ? 0 : pb + 1;
    }

    // epilogue: C layout col=lane&15, row=g*4+reg
    const int grow = row0 + rt * 16 + g * 4;
    const int bb_ = grow >> 11, tl = grow & 2047;
    #pragma unroll
    for (int ct = 0; ct < 3; ++ct) {
        const int n = (cbase + ct) * 16 + lo4;
        if (n < 64) {
            // K fragment-tiled
            const int ch = n >> 5, gi = (n >> 3) & 3, e = n & 7;
            const size_t base = (size_t)bb_ * 131072
                + (size_t)(((((tl >> 4) * 2 + ch) * 4 + gi) * 16 + (tl & 15)) * 8 + e);
            #pragma unroll
            for (int reg = 0; reg < 4; ++reg) {
                float v = acc[ct][reg];
                u16 hi = f2bf_trunc(v);
                kth[base + reg * 8] = hi;
                ktl[base + reg * 8] = f2bf_trunc(v - bf2f(hi));
            }
        } else if (n < 128) {
            #pragma unroll
            for (int reg = 0; reg < 4; ++reg) {
                float v = acc[ct][reg];   // already *8 (folded into Wq)
                u16 hi = f2bf_trunc(v);
                qh8[(size_t)(grow + reg) * HSn + (n - 64)] = hi;
                ql8[(size_t)(grow + reg) * HSn + (n - 64)] = f2bf_trunc(v - bf2f(hi));
            }
        } else {
            // V fragment-tiled
            const int h = n - 128;
            s16x4 pack;
            #pragma unroll
            for (int reg = 0; reg < 4; ++reg)
                pack[reg] = (short)f2bf_rne(acc[ct][reg]);
            const size_t vidx = (size_t)bb_ * 131072
                + (size_t)((tl >> 5) * 2048 + (h >> 4) * 512 + (h & 15) * 32
                           + ((tl >> 3) & 3) * 8 + (tl & 7));
            *(s16x4*)(vtt + vidx) = pack;
        }
    }
}

// ---------------- MFMA flash attention v3: coalesced fragment loads ----------------
struct KVset {
    bf16x8 kh0[2], kh1[2], kl0[2], kl1[2], vf[4];
};

__global__ __launch_bounds__(256, 2) void attn_kernel(
    const u16* __restrict__ qh8, const u16* __restrict__ ql8,
    const u16* __restrict__ kth, const u16* __restrict__ ktl,
    const u16* __restrict__ vtt, float* __restrict__ out)
{
    __shared__ __align__(16) unsigned char pbuf[4096];
    __shared__ __align__(16) float om_s[4][16][64];
    __shared__ float ml_s[4][16][2];

    const int tid  = threadIdx.x;
    const int wave = tid >> 6, lane = tid & 63;
    const int lo4  = lane & 15, g = lane >> 4;

    const int sblk = blockIdx.x >> 8, c = blockIdx.x & 255;
    const int tb = sblk ? 127 - (c >> 1) : (c >> 1);
    const int b  = 2 * sblk + (c & 1);
    const int t0 = tb * 16;

    const u16* qhp = qh8 + ((size_t)b * Tn + t0) * HSn;
    const u16* qlp = ql8 + ((size_t)b * Tn + t0) * HSn;
    const u16* kthb = kth + (size_t)b * 131072;
    const u16* ktlb = ktl + (size_t)b * 131072;
    const u16* vttb = vtt + (size_t)b * 131072;
    const int klane = lane * 8;
    const int vlane = lo4 * 32 + g * 8;

    bf16x8 qfh[2], qfl[2];
    #pragma unroll
    for (int ch = 0; ch < 2; ++ch) {
        qfh[ch] = *(const bf16x8*)(qhp + lo4 * HSn + ch * 32 + g * 8);
        qfl[ch] = *(const bf16x8*)(qlp + lo4 * HSn + ch * 32 + g * 8);
    }

    f32x4 O[4];
    #pragma unroll
    for (int n = 0; n < 4; ++n) O[n] = (f32x4){0.f, 0.f, 0.f, 0.f};
    float mrow[4], lrow[4];
    #pragma unroll
    for (int r = 0; r < 4; ++r) { mrow[r] = -1e30f; lrow[r] = 0.f; }

    const int nt = (t0 + 15) / 32 + 1;
    unsigned char* myPB = pbuf + wave * 1024;

    #define LOADSET(S, J)                                                     \
        {                                                                     \
            const u16* kb_ = kthb + (size_t)(2 * (J)) * 1024 + klane;         \
            const u16* lb_ = ktlb + (size_t)(2 * (J)) * 1024 + klane;         \
            S.kh0[0] = *(const bf16x8*)(kb_);                                 \
            S.kh1[0] = *(const bf16x8*)(kb_ + 512);                           \
            S.kh0[1] = *(const bf16x8*)(kb_ + 1024);                          \
            S.kh1[1] = *(const bf16x8*)(kb_ + 1536);                          \
            S.kl0[0] = *(const bf16x8*)(lb_);                                 \
            S.kl1[0] = *(const bf16x8*)(lb_ + 512);                           \
            S.kl0[1] = *(const bf16x8*)(lb_ + 1024);                          \
            S.kl1[1] = *(const bf16x8*)(lb_ + 1536);                          \
            const u16* vb_ = vttb + (size_t)(J) * 2048 + vlane;               \
            S.vf[0] = *(const bf16x8*)(vb_);                                  \
            S.vf[1] = *(const bf16x8*)(vb_ + 512);                            \
            S.vf[2] = *(const bf16x8*)(vb_ + 1024);                           \
            S.vf[3] = *(const bf16x8*)(vb_ + 1536);                           \
        }

    #define COMPUTE_ATT(S, J)                                                 \
        {                                                                     \
            const int s0 = (J) * 32;                                          \
            f32x4 accS[2];                                                    \
            __builtin_amdgcn_s_setprio(1);                                    \
            _Pragma("unroll")                                                 \
            for (int sb = 0; sb < 2; ++sb) {                                  \
                f32x4 a = (f32x4){0.f, 0.f, 0.f, 0.f};                        \
                a = __builtin_amdgcn_mfma_f32_16x16x32_bf16(qfh[0], S.kh0[sb], a, 0, 0, 0); \
                a = __builtin_amdgcn_mfma_f32_16x16x32_bf16(qfh[1], S.kh1[sb], a, 0, 0, 0); \
                a = __builtin_amdgcn_mfma_f32_16x16x32_bf16(qfl[0], S.kh0[sb], a, 0, 0, 0); \
                a = __builtin_amdgcn_mfma_f32_16x16x32_bf16(qfl[1], S.kh1[sb], a, 0, 0, 0); \
                a = __builtin_amdgcn_mfma_f32_16x16x32_bf16(qfh[0], S.kl0[sb], a, 0, 0, 0); \
                a = __builtin_amdgcn_mfma_f32_16x16x32_bf16(qfh[1], S.kl1[sb], a, 0, 0, 0); \
                accS[sb] = a;                                                 \
            }                                                                 \
            __builtin_amdgcn_s_setprio(0);                                    \
            _Pragma("unroll")                                                 \
            for (int reg = 0; reg < 4; ++reg) {                               \
                const int tg  = t0 + g * 4 + reg;                             \
                const int sg0 = s0 + lo4;                                     \
                const int sg1 = s0 + 16 + lo4;                                \
                float v0 = (sg0 <= tg) ? accS[0][reg] : -1e30f;               \
                float v1 = (sg1 <= tg) ? accS[1][reg] : -1e30f;               \
                float mt = fmaxf(v0, v1);                                     \
                mt = fmaxf(mt, __shfl_xor(mt, 1));                            \
                mt = fmaxf(mt, __shfl_xor(mt, 2));                            \
                mt = fmaxf(mt, __shfl_xor(mt, 4));                            \
                mt = fmaxf(mt, __shfl_xor(mt, 8));                            \
                float mn = fmaxf(mrow[reg], mt);                              \
                float p0 = (sg0 <= tg) ? __expf(v0 - mn) : 0.f;               \
                float p1 = (sg1 <= tg) ? __expf(v1 - mn) : 0.f;               \
                float ps = p0 + p1;                                           \
                ps += __shfl_xor(ps, 1);                                      \
                ps += __shfl_xor(ps, 2);                                      \
                ps += __shfl_xor(ps, 4);                                      \
                ps += __shfl_xor(ps, 8);                                      \
                float alpha = __expf(mrow[reg] - mn);                         \
                lrow[reg] = lrow[reg] * alpha + ps;                           \
                mrow[reg] = mn;                                               \
                _Pragma("unroll")                                             \
                for (int n = 0; n < 4; ++n) O[n][reg] *= alpha;               \
                const int irow = g * 4 + reg;                                 \
                *(u16*)(myPB + ((irow * 64 + lo4 * 2) ^ (reg << 4)))      = f2bf_rne(p0); \
                *(u16*)(myPB + ((irow * 64 + 32 + lo4 * 2) ^ (reg << 4))) = f2bf_rne(p1); \
            }                                                                 \
            bf16x8 pf = *(const bf16x8*)(myPB + ((lo4 * 64 + 16 * g) ^ ((lo4 & 3) << 4))); \
            __builtin_amdgcn_s_setprio(1);                                    \
            _Pragma("unroll")                                                 \
            for (int n = 0; n < 4; ++n)                                       \
                O[n] = __builtin_amdgcn_mfma_f32_16x16x32_bf16(pf, S.vf[n], O[n], 0, 0, 0); \
            __builtin_amdgcn_s_setprio(0);                                    \
        }

    KVset A, B;
    int j = wave;
    if (j < nt) LOADSET(A, j)
    while (j < nt) {
        if (j + 4 < nt) LOADSET(B, j + 4)
        COMPUTE_ATT(A, j)
        if (j + 4 < nt) {
            if (j + 8 < nt) LOADSET(A, j + 8)
            COMPUTE_ATT(B, j + 4)
        }
        j += 8;
    }

    // per-wave partials -> LDS
    #pragma unroll
    for (int n = 0; n < 4; ++n)
        #pragma unroll
        for (int reg = 0; reg < 4; ++reg)
            om_s[wave][g * 4 + reg][n * 16 + lo4] = O[n][reg];
    if (lo4 == 0) {
        #pragma unroll
        for (int reg = 0; reg < 4; ++reg) {
            ml_s[wave][g * 4 + reg][0] = mrow[reg];
            ml_s[wave][g * 4 + reg][1] = lrow[reg];
        }
    }
    __syncthreads();

    const int r  = tid >> 4;
    const int h4 = (tid & 15) * 4;
    float mw[4], lw[4], mstar = -1e30f;
    #pragma unroll
    for (int w = 0; w < 4; ++w) {
        mw[w] = ml_s[w][r][0];
        lw[w] = ml_s[w][r][1];
        mstar = fmaxf(mstar, mw[w]);
    }
    float lstar = 0.f, ew[4];
    #pragma unroll
    for (int w = 0; w < 4; ++w) { ew[w] = __expf(mw[w] - mstar); lstar += lw[w] * ew[w]; }
    float4 a4 = {0.f, 0.f, 0.f, 0.f};
    #pragma unroll
    for (int w = 0; w < 4; ++w) {
        float4 t4 = *(const float4*)&om_s[w][r][h4];
        a4.x += t4.x * ew[w]; a4.y += t4.y * ew[w];
        a4.z += t4.z * ew[w]; a4.w += t4.w * ew[w];
    }
    const float inv = 1.f / lstar;
    a4.x *= inv; a4.y *= inv; a4.z *= inv; a4.w *= inv;
    *(float4*)(out + ((size_t)b * Tn + t0 + r) * HSn + h4) = a4;
}

extern "C" void kernel_launch(void* const* d_in, const int* in_sizes, int n_in,
                              void* d_out, int out_size, void* d_ws, size_t ws_size,
                              hipStream_t stream) {
    const float* x  = (const float*)d_in[0];
    const float* Wk = (const float*)d_in[1];
    const float* Wq = (const float*)d_in[2];
    const float* Wv = (const float*)d_in[3];
    float* out = (float*)d_out;

    const size_t per = (size_t)Bn * Tn * HSn;   // 524288
    u16* qh8 = (u16*)d_ws;
    u16* ql8 = qh8 + per;
    u16* kth = ql8 + per;
    u16* ktl = kth + per;
    u16* vtt = ktl + per;
    u16* wtp = vtt + per;                       // 192*2048 u16 = 768 KB

    hipLaunchKernelGGL(wprep_kernel, dim3(16, 3), dim3(256), 0, stream,
                       Wk, Wq, Wv, wtp);
    hipLaunchKernelGGL(proj_gemm, dim3(256), dim3(512), 0, stream,
                       x, wtp, qh8, ql8, kth, ktl, vtt);
    hipLaunchKernelGGL(attn_kernel, dim3(512), dim3(256), 0, stream,
                       qh8, ql8, kth, ktl, vtt, out);
}